// Round 8
// baseline (530.941 us; speedup 1.0000x reference)
//
#include <hip/hip_runtime.h>
#include <math.h>

// ---------------------------------------------------------------------------
// SlotAttention fused forward. MFMA (bf16) attention path.
//   xb holds RAW bf16 x;  logit = rs*dot(x,w'') - rm*c1 + c0;  P = a*rs
//   rs/rm iteration-invariant: iter0 computes+stores (1MB), iters 1-2 load.
//   Input loads are lane-interleaved (flat idx k*256+t): each wave instruction
//   reads 1KB contiguous (was: 64-line gather — the r2-r7 defect).
//   y-fold: updates_pre[hq,j] = (g_j*(V - A1) + b_j*A0)/(A0 + eps*N)
//   GRU/MLP: gx = yflat @ Wfold^T (Wv folded into W_ih); k_gates + fused k_mlp.
// ---------------------------------------------------------------------------

#define NKV   4096
#define DD    256
#define HQN   32
#define EPSR  1e-8f

// workspace layout (float offsets)
#define WS_V      0                     // 262144
#define WS_A0     262144                // 1024
#define WS_A1     263168                // 1024
#define WS_C0     264192                // 1024
#define WS_C1     265216                // 1024
#define WS_SLOTA  266240                // 65536
#define WS_SLOTB  331776                // 65536
#define WS_WQT    397312                // 65536 fp32 Wq^T
#define WS_QF     462848                // 65536 fp32 qf[b][qi][256]
#define WS_WPGXH  528384                // 393216 (wp_bf 131072f | gxh [256][1536])
#define WS_WFT    921600                // 393216 uints: WfoldT2 [512][768]
#define WS_WHHT   1314816               // 98304 uints:  WhhT2   [128][768]
#define WS_W1T    1413120               // 131072 uints: W1T2    [128][1024]
#define WS_W2T    1544192               // 131072 uints: W2T2    [512][256]
#define WS_RS     1675264               // 131072 fp32 rs per token
#define WS_RM     1806336               // 131072 fp32 rm per token
// total 1937408 floats = 7.75 MB

typedef float f32x4 __attribute__((ext_vector_type(4)));
typedef short s16x8 __attribute__((ext_vector_type(8)));
typedef int   v2i   __attribute__((ext_vector_type(2)));

__device__ __forceinline__ unsigned bfr(float f) {
    unsigned u = __float_as_uint(f);
    return (u + 0x7fffu + ((u >> 16) & 1u)) >> 16;
}
__device__ __forceinline__ unsigned pk2(float lo, float hi) {
    return bfr(lo) | (bfr(hi) << 16);
}
__device__ __forceinline__ float bf2f(unsigned short us) {
    return __uint_as_float((unsigned)us << 16);
}
__device__ __forceinline__ float bflo(unsigned u) { return __uint_as_float(u << 16); }
__device__ __forceinline__ float bfhi(unsigned u) { return __uint_as_float(u & 0xffff0000u); }

__device__ __forceinline__ v2i tr_read(unsigned addr) {
    v2i d;
    asm volatile("ds_read_b64_tr_b16 %0, %1" : "=v"(d) : "v"(addr));
    return d;
}
__device__ __forceinline__ s16x8 mk_frag(v2i a, v2i b) {
    union { int i[4]; s16x8 s; } u;
    u.i[0] = a.x; u.i[1] = a.y; u.i[2] = b.x; u.i[3] = b.y;
    return u.s;
}

__global__ __launch_bounds__(256) void k_copy(const float* __restrict__ in,
                                              float* __restrict__ out, int n) {
    int i = blockIdx.x * 256 + threadIdx.x;
    if (i < n) out[i] = in[i];
}

// generic 32x32 tiled fp32 transpose: in[R][C] -> out[C][R]
__global__ __launch_bounds__(256) void k_tr(const float* __restrict__ in,
                                            float* __restrict__ out, int R, int C) {
    __shared__ float tile[32][33];
    int bx = blockIdx.x * 32, by = blockIdx.y * 32;
    int x = bx + threadIdx.x;
    for (int k = 0; k < 32; k += 8) {
        int y = by + threadIdx.y + k;
        if (x < C && y < R) tile[threadIdx.y + k][threadIdx.x] = in[(size_t)y * C + x];
    }
    __syncthreads();
    int r = by + threadIdx.x;
    for (int k = 0; k < 32; k += 8) {
        int c = bx + threadIdx.y + k;
        if (c < C && r < R) out[(size_t)c * R + r] = tile[threadIdx.x][threadIdx.y + k];
    }
}

// ---------------------------------------------------------------------------
// Wfold: one block per output row c. Wih row staged in LDS; Wv reads coalesced.
__global__ __launch_bounds__(256) void k_wfold(
    const float* __restrict__ Wih, const float* __restrict__ Wv,
    unsigned* __restrict__ WfT2)
{
    __shared__ float wr[256];
    const int c = blockIdx.x, t = threadIdx.x;
    wr[t] = Wih[(size_t)c * 256 + t];
    __syncthreads();
    const float2* wv2 = (const float2*)Wv;
    #pragma unroll
    for (int pp = 0; pp < 2; ++pp) {
        int P = pp * 256 + t;
        int h = P >> 7, p = P & 127;
        float f0 = 0.f, f1 = 0.f;
        #pragma unroll 8
        for (int d = 0; d < 64; ++d) {
            float a = wr[h * 64 + d];
            float2 v = wv2[(size_t)(h * 64 + d) * 128 + p];
            f0 = fmaf(a, v.x, f0); f1 = fmaf(a, v.y, f1);
        }
        WfT2[(size_t)P * 768 + c] = pk2(f0, f1);
    }
}

// transpose+pack: in fp32 [R][C] -> out uint [C/2][R]
__global__ __launch_bounds__(256) void k_trpack(
    const float* __restrict__ in, unsigned* __restrict__ out, int R, int C)
{
    const int c2 = blockIdx.x;
    const int t = threadIdx.x;
    for (int q = 0; q < R / 256; ++q) {
        int r = q * 256 + t;
        out[(size_t)c2 * R + r] = pk2(in[(size_t)r * C + 2 * c2],
                                      in[(size_t)r * C + 2 * c2 + 1]);
    }
}

// ---------------------------------------------------------------------------
// slotprep phase A: grid (32 b, 8 qi). LN(slots row qi) + qf row-GEMM vs wqt.
__global__ __launch_bounds__(256) void k_prep_a(
    const float* __restrict__ slots, const float* __restrict__ g_s, const float* __restrict__ b_s,
    const float* __restrict__ wqt, float* __restrict__ qf_g,
    float* __restrict__ V_g, float* __restrict__ A0_g, float* __restrict__ A1_g)
{
    __shared__ float s_row[256];
    __shared__ float red[8];
    const int t = threadIdx.x;
    const int b = blockIdx.x, qi = blockIdx.y;
    const int lane = t & 63, w = t >> 6;

    #pragma unroll
    for (int h = 0; h < 4; ++h)
        V_g[((size_t)b * 32 + h * 8 + qi) * 256 + t] = 0.f;
    if (t < 4) { A0_g[b * 32 + t * 8 + qi] = 0.f; A1_g[b * 32 + t * 8 + qi] = 0.f; }

    float v = slots[((size_t)b * 8 + qi) * 256 + t];
    float s0 = v, s1 = v * v;
    #pragma unroll
    for (int o = 32; o >= 1; o >>= 1) { s0 += __shfl_xor(s0, o, 64); s1 += __shfl_xor(s1, o, 64); }
    if (lane == 0) { red[w] = s0; red[4 + w] = s1; }
    __syncthreads();
    {
        float m = (red[0] + red[1] + red[2] + red[3]) * (1.f / 256.f);
        float q2 = (red[4] + red[5] + red[6] + red[7]) * (1.f / 256.f);
        float rs = rsqrtf(q2 - m * m + 1e-5f);
        s_row[t] = (v - m) * rs * g_s[t] + b_s[t];
    }
    __syncthreads();

    float a = 0.f;
    #pragma unroll 8
    for (int j = 0; j < 256; ++j)
        a = fmaf(s_row[j], wqt[j * 256 + t], a);
    qf_g[((size_t)b * 8 + qi) * 256 + t] = a;
}

// slotprep phase B: grid (32 b, 4 h). wkq fold + c0/c1 + wp_bf write.
__global__ __launch_bounds__(256) void k_prep_b(
    const float* __restrict__ qf_g, const float* __restrict__ Wk,
    const float* __restrict__ g_in, const float* __restrict__ b_in,
    unsigned short* __restrict__ wp_bf, float* __restrict__ c0_g, float* __restrict__ c1_g)
{
    __shared__ float qs[512];        // [qi][d]
    __shared__ float redc[4096];
    const int t = threadIdx.x;
    const int b = blockIdx.x, h = blockIdx.y;
    const int lane = t & 63, w = t >> 6;
    const float LNS = 0.125f * 1.44269504f;

    #pragma unroll
    for (int rep = 0; rep < 2; ++rep) {
        int idx = rep * 256 + t;
        int qi = idx >> 6, d = idx & 63;
        qs[idx] = qf_g[((size_t)b * 8 + qi) * 256 + h * 64 + d];
    }
    __syncthreads();

    float a2[8];
    #pragma unroll
    for (int qi = 0; qi < 8; ++qi) a2[qi] = 0.f;
    #pragma unroll 4
    for (int d = 0; d < 64; ++d) {
        float wv = Wk[(size_t)(h * 64 + d) * 256 + t];
        #pragma unroll
        for (int qi = 0; qi < 8; ++qi) a2[qi] = fmaf(qs[qi * 64 + d], wv, a2[qi]);
    }
    const float gv = g_in[t], bv = b_in[t];
    #pragma unroll
    for (int qi = 0; qi < 8; ++qi) {
        float kv = LNS * a2[qi];
        float we = kv * gv;
        wp_bf[((size_t)b * HQN + h * 8 + qi) * 256 + t] = (unsigned short)bfr(we);
        redc[qi * 256 + t] = we;
        redc[2048 + qi * 256 + t] = kv * bv;
    }
    __syncthreads();
    #pragma unroll
    for (int rep = 0; rep < 2; ++rep) {
        int r = w * 2 + rep;
        float sv1 = redc[r * 256 + lane] + redc[r * 256 + 64 + lane] +
                    redc[r * 256 + 128 + lane] + redc[r * 256 + 192 + lane];
        float sv0 = redc[2048 + r * 256 + lane] + redc[2048 + r * 256 + 64 + lane] +
                    redc[2048 + r * 256 + 128 + lane] + redc[2048 + r * 256 + 192 + lane];
        #pragma unroll
        for (int o = 32; o >= 1; o >>= 1) {
            sv1 += __shfl_xor(sv1, o, 64);
            sv0 += __shfl_xor(sv0, o, 64);
        }
        if (lane == 0) {
            c1_g[b * 32 + h * 8 + r] = sv1;
            c0_g[b * 32 + h * 8 + r] = sv0;
        }
    }
}

// ---------------------------------------------------------------------------
// Main fused MFMA pass. 1024 blocks, 4 chunks of 32 tokens each.
// Lane-interleaved loads: thread t loads float4 at flat idx k*256+t (each
// wave instruction = 1KB contiguous). Thread (w,l) holds granule l (float4)
// of tokens {4k+w : k=0..7}.
template<int STATS, int WVIS>
__global__ __launch_bounds__(256, 4) void k_attn(
    const float* __restrict__ inp, const unsigned short* __restrict__ wp_bf,
    const float* __restrict__ c0_g, const float* __restrict__ c1_g,
    float* __restrict__ V_g, float* __restrict__ A0_g, float* __restrict__ A1_g,
    float* __restrict__ rs_g, float* __restrict__ rm_g,
    float* __restrict__ out_vis, float* __restrict__ out_temp)
{
    __shared__ unsigned short xb[16 * 520];     // 16640 B, subtiled [nt][tok][16j]
    __shared__ unsigned short wl[8192];         // [hq][k] swizzled
    __shared__ unsigned short pt[1024];         // [hq][tok] swizzled bf16 P (= a*rs)
    __shared__ float stats[64];                 // [0..32): rs, [32..64): rm
    __shared__ float redm[64];
    __shared__ float reds[64];

    const int t = threadIdx.x;
    const int l = t & 63, w = t >> 6;
    const int g = l >> 4, li = l & 15;
    const int b = blockIdx.y, kb = blockIdx.x;

    char* xbB = (char*)xb;
    char* wlB = (char*)wl;
    char* ptB = (char*)pt;

    // stage W'' into LDS (swizzled rows [hq][k])
    {
        const uint4* wp4 = (const uint4*)wp_bf + ((size_t)b * 8192 + (t >> 3) * 256 + (t & 7) * 32) / 8;
        const int hq = t >> 3, sg = t & 7;
        #pragma unroll
        for (int q = 0; q < 4; ++q) {
            uint4 v = wp4[q];
            *(uint4*)(wlB + hq * 512 + (((sg * 4 + q) ^ (hq & 7)) * 16)) = v;
        }
    }

    const int Mt = w & 1, Nt = w >> 1;
    const int hqB = Nt * 16 + li;
    const float c0r = c0_g[b * 32 + hqB];
    const float c1r = c1_g[b * 32 + hqB];
    const int MtV = w >> 1, ntb = (w & 1) * 8;
    const int hqA = MtV * 16 + li;

    f32x4 av[8];
    #pragma unroll
    for (int u = 0; u < 8; ++u) av[u] = (f32x4){0.f, 0.f, 0.f, 0.f};
    float A0acc = 0.f, A1acc = 0.f;

    const unsigned xbase = (unsigned)(uintptr_t)xbB;
    const int cbase = kb * 4;

    // precomputed pack address: granule l -> subtile nt = ((l&31)>>2) + 8*(l>>5),
    // inner byte = ((l>>1)&1)*16 + (l&1)*8
    const int pk_nt   = ((l & 31) >> 2) + 8 * (l >> 5);
    const int pk_off  = pk_nt * 1040 + (((l >> 1) & 1) * 16 + (l & 1) * 8);

    #pragma unroll
    for (int ci = 0; ci < 4; ++ci) {
        const int n0 = (cbase + ci) * 32;

        // ---- lane-interleaved coalesced loads: 8 x 1KB/wave-instr ----
        const float4* cb4 = (const float4*)(inp + ((size_t)b * NKV + n0) * 256);
        float4 ld[8];
        #pragma unroll
        for (int k = 0; k < 8; ++k) ld[k] = cb4[k * 256 + t];

        if (!STATS) {
            if (t < 32) stats[t] = rs_g[b * 4096 + n0 + t];
            else if (t < 64) stats[t] = rm_g[b * 4096 + n0 + t - 32];
        } else {
            // wave w owns tokens {4k+w}; full-wave butterfly per token
            #pragma unroll
            for (int k = 0; k < 8; ++k) {
                float a0 = ld[k].x + ld[k].y + ld[k].z + ld[k].w;
                float a1 = fmaf(ld[k].x, ld[k].x, fmaf(ld[k].y, ld[k].y,
                           fmaf(ld[k].z, ld[k].z, ld[k].w * ld[k].w)));
                #pragma unroll
                for (int o = 32; o >= 1; o >>= 1) {
                    a0 += __shfl_xor(a0, o, 64);
                    a1 += __shfl_xor(a1, o, 64);
                }
                if (l == 0) {
                    float m  = a0 * (1.f / 256.f);
                    float rs = rsqrtf(a1 * (1.f / 256.f) - m * m + 1e-5f);
                    int tok = 4 * k + w;
                    stats[tok] = rs;
                    stats[32 + tok] = rs * m;
                    rs_g[b * 4096 + n0 + tok] = rs;
                    rm_g[b * 4096 + n0 + tok] = rs * m;
                }
            }
        }
        // ---- pack raw bf16 into xb (8B per thread per k) ----
        #pragma unroll
        for (int k = 0; k < 8; ++k) {
            int tok = 4 * k + w;
            uint2 pw;
            pw.x = pk2(ld[k].x, ld[k].y);
            pw.y = pk2(ld[k].z, ld[k].w);
            *(uint2*)(xbB + pk_off + tok * 32) = pw;
        }
        __syncthreads();   // A: xb + stats ready

        // ---- S = X * W''^T (raw-x accumulate) ----
        f32x4 accS = (f32x4){0.f, 0.f, 0.f, 0.f};
        #pragma unroll
        for (int kk = 0; kk < 8; ++kk) {
            s16x8 af = *(const s16x8*)(xbB + (kk * 2 + (g >> 1)) * 1040 +
                                       (Mt * 16 + li) * 32 + (g & 1) * 16);
            s16x8 bf = *(const s16x8*)(wlB + hqB * 512 + (((kk * 4 + g) ^ (hqB & 7)) * 16));
            accS = __builtin_amdgcn_mfma_f32_16x16x32_bf16(af, bf, accS, 0, 0, 0);
        }

        // ---- logits + merged-barrier joint softmax over 32 hq ----
        float lg[4], rsv[4], rmv[4], mh[4], ex[4], aa[4];
        #pragma unroll
        for (int r = 0; r < 4; ++r) {
            int tokr = Mt * 16 + g * 4 + r;
            rsv[r] = stats[tokr];
            rmv[r] = stats[32 + tokr];
            lg[r] = fmaf(rsv[r], accS[r], fmaf(-rmv[r], c1r, c0r));
        }
        #pragma unroll
        for (int r = 0; r < 4; ++r) {
            float v = lg[r];
            v = fmaxf(v, __shfl_xor(v, 1, 64));
            v = fmaxf(v, __shfl_xor(v, 2, 64));
            v = fmaxf(v, __shfl_xor(v, 4, 64));
            v = fmaxf(v, __shfl_xor(v, 8, 64));
            mh[r] = v;
            ex[r] = exp2f(lg[r] - v);
            float s = ex[r];
            s += __shfl_xor(s, 1, 64);
            s += __shfl_xor(s, 2, 64);
            s += __shfl_xor(s, 4, 64);
            s += __shfl_xor(s, 8, 64);
            if (li == 0) {
                int tokr = Mt * 16 + g * 4 + r;
                redm[tokr * 2 + Nt] = v;
                reds[tokr * 2 + Nt] = s;
            }
        }
        __syncthreads();   // B
        #pragma unroll
        for (int r = 0; r < 4; ++r) {
            int tokr = Mt * 16 + g * 4 + r;
            float m0 = redm[tokr * 2], m1 = redm[tokr * 2 + 1];
            float mx = fmaxf(m0, m1);
            float tot = reds[tokr * 2] * exp2f(m0 - mx) + reds[tokr * 2 + 1] * exp2f(m1 - mx);
            aa[r] = ex[r] * (exp2f(mh[r] - mx) / tot);
            A0acc += aa[r];
            A1acc = fmaf(aa[r], rmv[r], A1acc);
        }
        {
            uint2 pw;
            pw.x = pk2(aa[0] * rsv[0], aa[1] * rsv[1]);
            pw.y = pk2(aa[2] * rsv[2], aa[3] * rsv[3]);
            int tokb = Mt * 16 + g * 4;
            int slot = (tokb >> 3) ^ ((hqB >> 1) & 3);
            *(uint2*)(ptB + hqB * 64 + slot * 16 + (tokb & 7) * 2) = pw;
        }
        __syncthreads();   // D: P ready

        if (WVIS) {
            int tk = t >> 3, q = t & 7;
            float sv = 0.f;
            #pragma unroll
            for (int h = 0; h < 4; ++h) {
                int hq = h * 8 + q;
                int slot = (tk >> 3) ^ ((hq >> 1) & 3);
                sv += bf2f(*(const unsigned short*)(ptB + hq * 64 + slot * 16 + (tk & 7) * 2));
            }
            float vv = sv / stats[tk];          // undo the rs fold (P = a*rs)
            size_t o = ((size_t)b * NKV + n0 + tk) * 8 + q;
            out_vis[o] = vv; out_temp[o] = vv;
        }

        // ---- V += P^T(A) * X(B) via tr-reads ----
        {
            s16x8 pa = *(const s16x8*)(ptB + hqA * 64 + ((g ^ ((hqA >> 1) & 3)) * 16));
            unsigned abase = xbase + g * 256 + li * 8;
            v2i t0a = tr_read(abase + (ntb + 0) * 1040);
            v2i t0b = tr_read(abase + (ntb + 0) * 1040 + 128);
            v2i t1a = tr_read(abase + (ntb + 1) * 1040);
            v2i t1b = tr_read(abase + (ntb + 1) * 1040 + 128);
            v2i t2a = tr_read(abase + (ntb + 2) * 1040);
            v2i t2b = tr_read(abase + (ntb + 2) * 1040 + 128);
            v2i t3a = tr_read(abase + (ntb + 3) * 1040);
            v2i t3b = tr_read(abase + (ntb + 3) * 1040 + 128);
            asm volatile("s_waitcnt lgkmcnt(0)" ::: "memory");
            __builtin_amdgcn_sched_barrier(0);
            av[0] = __builtin_amdgcn_mfma_f32_16x16x32_bf16(pa, mk_frag(t0a, t0b), av[0], 0, 0, 0);
            av[1] = __builtin_amdgcn_mfma_f32_16x16x32_bf16(pa, mk_frag(t1a, t1b), av[1], 0, 0, 0);
            av[2] = __builtin_amdgcn_mfma_f32_16x16x32_bf16(pa, mk_frag(t2a, t2b), av[2], 0, 0, 0);
            av[3] = __builtin_amdgcn_mfma_f32_16x16x32_bf16(pa, mk_frag(t3a, t3b), av[3], 0, 0, 0);
            v2i t4a = tr_read(abase + (ntb + 4) * 1040);
            v2i t4b = tr_read(abase + (ntb + 4) * 1040 + 128);
            v2i t5a = tr_read(abase + (ntb + 5) * 1040);
            v2i t5b = tr_read(abase + (ntb + 5) * 1040 + 128);
            v2i t6a = tr_read(abase + (ntb + 6) * 1040);
            v2i t6b = tr_read(abase + (ntb + 6) * 1040 + 128);
            v2i t7a = tr_read(abase + (ntb + 7) * 1040);
            v2i t7b = tr_read(abase + (ntb + 7) * 1040 + 128);
            asm volatile("s_waitcnt lgkmcnt(0)" ::: "memory");
            __builtin_amdgcn_sched_barrier(0);
            av[4] = __builtin_amdgcn_mfma_f32_16x16x32_bf16(pa, mk_frag(t4a, t4b), av[4], 0, 0, 0);
            av[5] = __builtin_amdgcn_mfma_f32_16x16x32_bf16(pa, mk_frag(t5a, t5b), av[5], 0, 0, 0);
            av[6] = __builtin_amdgcn_mfma_f32_16x16x32_bf16(pa, mk_frag(t6a, t6b), av[6], 0, 0, 0);
            av[7] = __builtin_amdgcn_mfma_f32_16x16x32_bf16(pa, mk_frag(t7a, t7b), av[7], 0, 0, 0);
        }
        __syncthreads();   // E: xb/pt free for next chunk
    }

    // ---- final global accumulation ----
    A0acc += __shfl_xor(A0acc, 16, 64); A0acc += __shfl_xor(A0acc, 32, 64);
    A1acc += __shfl_xor(A1acc, 16, 64); A1acc += __shfl_xor(A1acc, 32, 64);
    if (g == 0) {
        atomicAdd(A0_g + b * 32 + hqB, A0acc);
        atomicAdd(A1_g + b * 32 + hqB, A1acc);
    }
    #pragma unroll
    for (int i = 0; i < 8; ++i) {
        int j = (ntb + i) * 16 + li;
        #pragma unroll
        for (int r = 0; r < 4; ++r) {
            int hq = MtV * 16 + g * 4 + r;
            atomicAdd(V_g + ((size_t)b * 32 + hq) * 256 + j, av[i][r]);
        }
    }
}

// ---------------------------------------------------------------------------
// gx | gh GEMMs. grid (6, 64). chunk-0 blocks also zero slot_nxt rows.
__global__ __launch_bounds__(256) void k_gates(
    const float* __restrict__ V_g, const float* __restrict__ A0_g,
    const float* __restrict__ A1_g,
    const float* __restrict__ g_in, const float* __restrict__ b_in,
    const float* __restrict__ slot_cur,
    const unsigned* __restrict__ WfT2, const unsigned* __restrict__ WhhT2,
    float* __restrict__ gxh, float* __restrict__ slot_nxt)
{
    __shared__ __align__(16) float aT[1024 * 4];   // [k][rr]
    const int t = threadIdx.x;
    const int rg = blockIdx.y;
    const int chunk = blockIdx.x;
    const int row0 = rg * 4;
    float acc0 = 0.f, acc1 = 0.f, acc2 = 0.f, acc3 = 0.f;

    if (chunk == 0) {
        #pragma unroll
        for (int rr = 0; rr < 4; ++rr)
            slot_nxt[(size_t)(row0 + rr) * 256 + t] = 0.f;
    }

    if (chunk < 3) {
        const int b = rg >> 1, qi0 = (rg & 1) * 4;
        const float gt = g_in[t], bt = b_in[t];
        #pragma unroll
        for (int kk = 0; kk < 4; ++kk) {
            float4 y4;
            #pragma unroll
            for (int rr = 0; rr < 4; ++rr) {
                int hq = kk * 8 + qi0 + rr;
                float A0 = A0_g[b * 32 + hq], A1 = A1_g[b * 32 + hq];
                float den = A0 + EPSR * (float)NKV;
                float vv = V_g[((size_t)b * 32 + hq) * 256 + t];
                float yv = (gt * (vv - A1) + bt * A0) / den;
                ((float*)&y4)[rr] = yv;
            }
            *(float4*)(aT + (kk * 256 + t) * 4) = y4;
        }
        __syncthreads();
        const unsigned* wp = WfT2 + chunk * 256 + t;
        #pragma unroll 4
        for (int k2 = 0; k2 < 512; ++k2) {
            unsigned wv = wp[(size_t)k2 * 768];
            float w0 = bflo(wv), w1 = bfhi(wv);
            float4 a0 = *(const float4*)(aT + 8 * k2);
            float4 a1 = *(const float4*)(aT + 8 * k2 + 4);
            acc0 = fmaf(a0.x, w0, acc0); acc0 = fmaf(a1.x, w1, acc0);
            acc1 = fmaf(a0.y, w0, acc1); acc1 = fmaf(a1.y, w1, acc1);
            acc2 = fmaf(a0.z, w0, acc2); acc2 = fmaf(a1.z, w1, acc2);
            acc3 = fmaf(a0.w, w0, acc3); acc3 = fmaf(a1.w, w1, acc3);
        }
        float* go = gxh + (size_t)row0 * 1536 + chunk * 256 + t;
        go[0] = acc0; go[1536] = acc1; go[3072] = acc2; go[4608] = acc3;
    } else {
        const int gc = chunk - 3;
        {
            float4 y4;
            #pragma unroll
            for (int rr = 0; rr < 4; ++rr)
                ((float*)&y4)[rr] = slot_cur[(size_t)(row0 + rr) * 256 + t];
            *(float4*)(aT + t * 4) = y4;
        }
        __syncthreads();
        const unsigned* wp = WhhT2 + gc * 256 + t;
        #pragma unroll 4
        for (int k2 = 0; k2 < 128; ++k2) {
            unsigned wv = wp[(size_t)k2 * 768];
            float w0 = bflo(wv), w1 = bfhi(wv);
            float4 a0 = *(const float4*)(aT + 8 * k2);
            float4 a1 = *(const float4*)(aT + 8 * k2 + 4);
            acc0 = fmaf(a0.x, w0, acc0); acc0 = fmaf(a1.x, w1, acc0);
            acc1 = fmaf(a0.y, w0, acc1); acc1 = fmaf(a1.y, w1, acc1);
            acc2 = fmaf(a0.z, w0, acc2); acc2 = fmaf(a1.z, w1, acc2);
            acc3 = fmaf(a0.w, w0, acc3); acc3 = fmaf(a1.w, w1, acc3);
        }
        float* go = gxh + (size_t)row0 * 1536 + 768 + gc * 256 + t;
        go[0] = acc0; go[1536] = acc1; go[3072] = acc2; go[4608] = acc3;
    }
}

// ---------------------------------------------------------------------------
// Fused GRU elementwise + LN + MLP(W1,relu,W2) with h1 in LDS. grid (4, 64).
__global__ __launch_bounds__(256) void k_mlp(
    const float* __restrict__ gxh, const float* __restrict__ slot_cur,
    const float* __restrict__ bih, const float* __restrict__ bhh,
    const float* __restrict__ gm, const float* __restrict__ bm,
    const unsigned* __restrict__ W1T2, const float* __restrict__ b1,
    const unsigned* __restrict__ W2T2, const float* __restrict__ b2,
    float* __restrict__ slot_nxt)
{
    __shared__ __align__(16) float mT[1024];
    __shared__ float sm_l[4][256];
    __shared__ float h1_l[4][256];
    __shared__ float lnst[8];
    const int t = threadIdx.x;
    const int rg = blockIdx.y, chunk = blockIdx.x;
    const int row0 = rg * 4;
    const int lane = t & 63, w = t >> 6;

    const float bi0 = bih[t], bi1 = bih[256 + t], bi2 = bih[512 + t];
    const float bh0 = bhh[t], bh1 = bhh[256 + t], bh2 = bhh[512 + t];
    float smid[4];
    #pragma unroll
    for (int rr = 0; rr < 4; ++rr) {
        const float* gr = gxh + (size_t)(row0 + rr) * 1536;
        float gx0 = gr[t], gx1 = gr[256 + t], gx2 = gr[512 + t];
        float gh0 = gr[768 + t], gh1 = gr[1024 + t], gh2 = gr[1280 + t];
        float spv = slot_cur[(size_t)(row0 + rr) * 256 + t];
        float r = 1.f / (1.f + __expf(-(gx0 + bi0 + gh0 + bh0)));
        float z = 1.f / (1.f + __expf(-(gx1 + bi1 + gh1 + bh1)));
        float n = tanhf(gx2 + bi2 + r * (gh2 + bh2));
        smid[rr] = (1.f - z) * n + z * spv;
        sm_l[rr][t] = smid[rr];
    }
    __syncthreads();
    {
        float4 v = *(const float4*)(&sm_l[w][lane * 4]);
        float s0 = v.x + v.y + v.z + v.w;
        float s1 = v.x * v.x + v.y * v.y + v.z * v.z + v.w * v.w;
        #pragma unroll
        for (int o = 32; o >= 1; o >>= 1) { s0 += __shfl_xor(s0, o, 64); s1 += __shfl_xor(s1, o, 64); }
        if (lane == 0) {
            float mu = s0 * (1.f / 256.f);
            lnst[w * 2] = mu;
            lnst[w * 2 + 1] = rsqrtf(s1 * (1.f / 256.f) - mu * mu + 1e-5f);
        }
    }
    __syncthreads();
    {
        const float gmt = gm[t], bmt = bm[t];
        float4 m4;
        #pragma unroll
        for (int rr = 0; rr < 4; ++rr)
            ((float*)&m4)[rr] = (smid[rr] - lnst[rr * 2]) * lnst[rr * 2 + 1] * gmt + bmt;
        *(float4*)(mT + t * 4) = m4;
    }
    __syncthreads();

    {
        float acc0 = 0.f, acc1 = 0.f, acc2 = 0.f, acc3 = 0.f;
        const unsigned* wp = W1T2 + chunk * 256 + t;
        #pragma unroll 4
        for (int k2 = 0; k2 < 128; ++k2) {
            unsigned wv = wp[(size_t)k2 * 1024];
            float w0 = bflo(wv), w1 = bfhi(wv);
            float4 a0 = *(const float4*)(mT + 8 * k2);
            float4 a1 = *(const float4*)(mT + 8 * k2 + 4);
            acc0 = fmaf(a0.x, w0, acc0); acc0 = fmaf(a1.x, w1, acc0);
            acc1 = fmaf(a0.y, w0, acc1); acc1 = fmaf(a1.y, w1, acc1);
            acc2 = fmaf(a0.z, w0, acc2); acc2 = fmaf(a1.z, w1, acc2);
            acc3 = fmaf(a0.w, w0, acc3); acc3 = fmaf(a1.w, w1, acc3);
        }
        const float b1t = b1[chunk * 256 + t];
        h1_l[0][t] = fmaxf(acc0 + b1t, 0.f);
        h1_l[1][t] = fmaxf(acc1 + b1t, 0.f);
        h1_l[2][t] = fmaxf(acc2 + b1t, 0.f);
        h1_l[3][t] = fmaxf(acc3 + b1t, 0.f);
    }
    __syncthreads();

    {
        float o0 = 0.f, o1 = 0.f, o2 = 0.f, o3 = 0.f;
        const unsigned* wp = W2T2 + (size_t)(chunk * 128) * 256 + t;
        #pragma unroll 4
        for (int k2 = 0; k2 < 128; ++k2) {
            unsigned wv = wp[(size_t)k2 * 256];
            float w0 = bflo(wv), w1 = bfhi(wv);
            float a00 = h1_l[0][2 * k2], a01 = h1_l[0][2 * k2 + 1];
            float a10 = h1_l[1][2 * k2], a11 = h1_l[1][2 * k2 + 1];
            float a20 = h1_l[2][2 * k2], a21 = h1_l[2][2 * k2 + 1];
            float a30 = h1_l[3][2 * k2], a31 = h1_l[3][2 * k2 + 1];
            o0 = fmaf(a00, w0, o0); o0 = fmaf(a01, w1, o0);
            o1 = fmaf(a10, w0, o1); o1 = fmaf(a11, w1, o1);
            o2 = fmaf(a20, w0, o2); o2 = fmaf(a21, w1, o2);
            o3 = fmaf(a30, w0, o3); o3 = fmaf(a31, w1, o3);
        }
        const float b2t = b2[t];
        float base0 = (chunk == 0) ? smid[0] + b2t : 0.f;
        float base1 = (chunk == 0) ? smid[1] + b2t : 0.f;
        float base2 = (chunk == 0) ? smid[2] + b2t : 0.f;
        float base3 = (chunk == 0) ? smid[3] + b2t : 0.f;
        atomicAdd(slot_nxt + (size_t)(row0 + 0) * 256 + t, o0 + base0);
        atomicAdd(slot_nxt + (size_t)(row0 + 1) * 256 + t, o1 + base1);
        atomicAdd(slot_nxt + (size_t)(row0 + 2) * 256 + t, o2 + base2);
        atomicAdd(slot_nxt + (size_t)(row0 + 3) * 256 + t, o3 + base3);
    }
}

// ---------------------------------------------------------------------------
extern "C" void kernel_launch(void* const* d_in, const int* in_sizes, int n_in,
                              void* d_out, int out_size, void* d_ws, size_t ws_size,
                              hipStream_t stream) {
    const float* inp     = (const float*)d_in[0];
    const float* slots0  = (const float*)d_in[1];
    const float* ln_in_g = (const float*)d_in[2];
    const float* ln_in_b = (const float*)d_in[3];
    const float* ln_s_g  = (const float*)d_in[4];
    const float* ln_s_b  = (const float*)d_in[5];
    const float* ln_m_g  = (const float*)d_in[6];
    const float* ln_m_b  = (const float*)d_in[7];
    const float* Wq  = (const float*)d_in[8];
    const float* Wk  = (const float*)d_in[9];
    const float* Wv  = (const float*)d_in[10];
    const float* Wih = (const float*)d_in[11];
    const float* Whh = (const float*)d_in[12];
    const float* bih = (const float*)d_in[13];
    const float* bhh = (const float*)d_in[14];
    const float* W1  = (const float*)d_in[15];
    const float* b1  = (const float*)d_in[16];
    const float* W2  = (const float*)d_in[17];
    const float* b2  = (const float*)d_in[18];

    float* ws = (float*)d_ws;
    float* V_g   = ws + WS_V;
    float* A0_g  = ws + WS_A0;
    float* A1_g  = ws + WS_A1;
    float* c0_g  = ws + WS_C0;
    float* c1_g  = ws + WS_C1;
    float* slotA = ws + WS_SLOTA;
    float* slotB = ws + WS_SLOTB;
    float* wqt   = ws + WS_WQT;
    float* qf_g  = ws + WS_QF;
    float* gxh   = ws + WS_WPGXH;    // aliased with wp_bf (disjoint lifetimes)
    unsigned short* wp_bf = (unsigned short*)(ws + WS_WPGXH);
    unsigned* WfT2  = (unsigned*)(ws + WS_WFT);
    unsigned* WhhT2 = (unsigned*)(ws + WS_WHHT);
    unsigned* W1T2  = (unsigned*)(ws + WS_W1T);
    unsigned* W2T2  = (unsigned*)(ws + WS_W2T);
    float* rs_g = ws + WS_RS;
    float* rm_g = ws + WS_RM;

    float* out_slots = (float*)d_out;
    float* out_vis   = out_slots + 32 * 8 * 256;
    float* out_temp  = out_vis + 32 * 4096 * 8;

    k_tr<<<dim3(8, 8), dim3(32, 8), 0, stream>>>(Wq, wqt, 256, 256);
    k_wfold<<<768, 256, 0, stream>>>(Wih, Wv, WfT2);
    k_trpack<<<128, 256, 0, stream>>>(Whh, WhhT2, 768, 256);
    k_trpack<<<128, 256, 0, stream>>>(W1, W1T2, 1024, 256);
    k_trpack<<<512, 256, 0, stream>>>(W2, W2T2, 256, 1024);
    k_copy<<<256, 256, 0, stream>>>(slots0, slotA, 65536);

    for (int it = 0; it < 3; ++it) {
        float* cur = (it & 1) ? slotB : slotA;
        float* nxt = (it & 1) ? slotA : slotB;
        k_prep_a<<<dim3(32, 8), 256, 0, stream>>>(cur, ln_s_g, ln_s_b, wqt, qf_g,
                                                  V_g, A0_g, A1_g);
        k_prep_b<<<dim3(32, 4), 256, 0, stream>>>(qf_g, Wk, ln_in_g, ln_in_b,
                                                  wp_bf, c0_g, c1_g);
        if (it == 0)
            k_attn<1, 0><<<dim3(32, 32), 256, 0, stream>>>(
                inp, wp_bf, c0_g, c1_g, V_g, A0_g, A1_g, rs_g, rm_g, out_vis, out_temp);
        else if (it == 1)
            k_attn<0, 0><<<dim3(32, 32), 256, 0, stream>>>(
                inp, wp_bf, c0_g, c1_g, V_g, A0_g, A1_g, rs_g, rm_g, out_vis, out_temp);
        else
            k_attn<0, 1><<<dim3(32, 32), 256, 0, stream>>>(
                inp, wp_bf, c0_g, c1_g, V_g, A0_g, A1_g, rs_g, rm_g, out_vis, out_temp);
        k_gates<<<dim3(6, 64), 256, 0, stream>>>(
            V_g, A0_g, A1_g, ln_in_g, ln_in_b, cur, WfT2, WhhT2, gxh, nxt);
        k_mlp<<<dim3(4, 64), 256, 0, stream>>>(
            gxh, cur, bih, bhh, ln_m_g, ln_m_b, W1T2, b1, W2T2, b2, nxt);
    }
    k_copy<<<256, 256, 0, stream>>>(slotB, out_slots, 65536);
}

// Round 9
// 476.255 us; speedup vs baseline: 1.1148x; 1.1148x over previous
//
#include <hip/hip_runtime.h>
#include <math.h>

// ---------------------------------------------------------------------------
// SlotAttention fused forward. MFMA (bf16) attention path.
//   xb holds RAW bf16 x (double-buffered);  logit = rs*dot(x,w'') - rm*c1 + c0
//   P = a*rs;  rs/rm iteration-invariant (iter0 computes+stores, iters 1-2 load)
//   V partials: plain stores to Vpart[b,kb,hq,j], reduced by k_vred (no atomics)
//   y-fold: updates_pre[hq,j] = (g_j*(V - A1) + b_j*A0)/(A0 + eps*N)
//   GRU/MLP: gx = yflat @ Wfold^T (Wv folded into W_ih); k_gates + fused k_mlp.
// ---------------------------------------------------------------------------

#define NKV   4096
#define DD    256
#define HQN   32
#define EPSR  1e-8f

// workspace layout (float offsets) — ws_size proven >= 74 MB (r5)
#define WS_V      0                     // 262144
#define WS_A0     262144                // 1024
#define WS_A1     263168                // 1024
#define WS_C0     264192                // 1024
#define WS_C1     265216                // 1024
#define WS_SLOTA  266240                // 65536
#define WS_SLOTB  331776                // 65536
#define WS_WQT    397312                // 65536 fp32 Wq^T
#define WS_QF     462848                // 65536 fp32 qf[b][qi][256]
#define WS_WPGXH  528384                // 393216 (wp_bf 131072f | gxh [256][1536])
#define WS_WFT    921600                // 393216 uints: WfoldT2 [512][768]
#define WS_WHHT   1314816               // 98304 uints:  WhhT2   [128][768]
#define WS_W1T    1413120               // 131072 uints: W1T2    [128][1024]
#define WS_W2T    1544192               // 131072 uints: W2T2    [512][256]
#define WS_RS     1675264               // 131072 fp32 rs per token
#define WS_RM     1806336               // 131072 fp32 rm per token
#define WS_VPART  1937408               // 8388608 fp32 Vpart[b*32+kb][32hq][256j] = 32MB
// total 10326016 floats ≈ 41.3 MB

typedef float f32x4 __attribute__((ext_vector_type(4)));
typedef short s16x8 __attribute__((ext_vector_type(8)));
typedef int   v2i   __attribute__((ext_vector_type(2)));

__device__ __forceinline__ unsigned bfr(float f) {
    unsigned u = __float_as_uint(f);
    return (u + 0x7fffu + ((u >> 16) & 1u)) >> 16;
}
__device__ __forceinline__ unsigned pk2(float lo, float hi) {
    return bfr(lo) | (bfr(hi) << 16);
}
__device__ __forceinline__ float bf2f(unsigned short us) {
    return __uint_as_float((unsigned)us << 16);
}
__device__ __forceinline__ float bflo(unsigned u) { return __uint_as_float(u << 16); }
__device__ __forceinline__ float bfhi(unsigned u) { return __uint_as_float(u & 0xffff0000u); }

__device__ __forceinline__ v2i tr_read(unsigned addr) {
    v2i d;
    asm volatile("ds_read_b64_tr_b16 %0, %1" : "=v"(d) : "v"(addr));
    return d;
}
__device__ __forceinline__ s16x8 mk_frag(v2i a, v2i b) {
    union { int i[4]; s16x8 s; } u;
    u.i[0] = a.x; u.i[1] = a.y; u.i[2] = b.x; u.i[3] = b.y;
    return u.s;
}

__global__ __launch_bounds__(256) void k_copy(const float* __restrict__ in,
                                              float* __restrict__ out, int n) {
    int i = blockIdx.x * 256 + threadIdx.x;
    if (i < n) out[i] = in[i];
}

// generic 32x32 tiled fp32 transpose: in[R][C] -> out[C][R]
__global__ __launch_bounds__(256) void k_tr(const float* __restrict__ in,
                                            float* __restrict__ out, int R, int C) {
    __shared__ float tile[32][33];
    int bx = blockIdx.x * 32, by = blockIdx.y * 32;
    int x = bx + threadIdx.x;
    for (int k = 0; k < 32; k += 8) {
        int y = by + threadIdx.y + k;
        if (x < C && y < R) tile[threadIdx.y + k][threadIdx.x] = in[(size_t)y * C + x];
    }
    __syncthreads();
    int r = by + threadIdx.x;
    for (int k = 0; k < 32; k += 8) {
        int c = bx + threadIdx.y + k;
        if (c < C && r < R) out[(size_t)c * R + r] = tile[threadIdx.x][threadIdx.y + k];
    }
}

// ---------------------------------------------------------------------------
// Wfold: one block per output row c.
__global__ __launch_bounds__(256) void k_wfold(
    const float* __restrict__ Wih, const float* __restrict__ Wv,
    unsigned* __restrict__ WfT2)
{
    __shared__ float wr[256];
    const int c = blockIdx.x, t = threadIdx.x;
    wr[t] = Wih[(size_t)c * 256 + t];
    __syncthreads();
    const float2* wv2 = (const float2*)Wv;
    #pragma unroll
    for (int pp = 0; pp < 2; ++pp) {
        int P = pp * 256 + t;
        int h = P >> 7, p = P & 127;
        float f0 = 0.f, f1 = 0.f;
        #pragma unroll 8
        for (int d = 0; d < 64; ++d) {
            float a = wr[h * 64 + d];
            float2 v = wv2[(size_t)(h * 64 + d) * 128 + p];
            f0 = fmaf(a, v.x, f0); f1 = fmaf(a, v.y, f1);
        }
        WfT2[(size_t)P * 768 + c] = pk2(f0, f1);
    }
}

// transpose+pack: in fp32 [R][C] -> out uint [C/2][R]
__global__ __launch_bounds__(256) void k_trpack(
    const float* __restrict__ in, unsigned* __restrict__ out, int R, int C)
{
    const int c2 = blockIdx.x;
    const int t = threadIdx.x;
    for (int q = 0; q < R / 256; ++q) {
        int r = q * 256 + t;
        out[(size_t)c2 * R + r] = pk2(in[(size_t)r * C + 2 * c2],
                                      in[(size_t)r * C + 2 * c2 + 1]);
    }
}

// ---------------------------------------------------------------------------
// slotprep phase A: grid (32 b, 8 qi). LN(slots row qi) + qf row-GEMM vs wqt.
__global__ __launch_bounds__(256) void k_prep_a(
    const float* __restrict__ slots, const float* __restrict__ g_s, const float* __restrict__ b_s,
    const float* __restrict__ wqt, float* __restrict__ qf_g,
    float* __restrict__ A0_g, float* __restrict__ A1_g)
{
    __shared__ float s_row[256];
    __shared__ float red[8];
    const int t = threadIdx.x;
    const int b = blockIdx.x, qi = blockIdx.y;
    const int lane = t & 63, w = t >> 6;

    if (t < 4) { A0_g[b * 32 + t * 8 + qi] = 0.f; A1_g[b * 32 + t * 8 + qi] = 0.f; }

    float v = slots[((size_t)b * 8 + qi) * 256 + t];
    float s0 = v, s1 = v * v;
    #pragma unroll
    for (int o = 32; o >= 1; o >>= 1) { s0 += __shfl_xor(s0, o, 64); s1 += __shfl_xor(s1, o, 64); }
    if (lane == 0) { red[w] = s0; red[4 + w] = s1; }
    __syncthreads();
    {
        float m = (red[0] + red[1] + red[2] + red[3]) * (1.f / 256.f);
        float q2 = (red[4] + red[5] + red[6] + red[7]) * (1.f / 256.f);
        float rs = rsqrtf(q2 - m * m + 1e-5f);
        s_row[t] = (v - m) * rs * g_s[t] + b_s[t];
    }
    __syncthreads();

    float a = 0.f;
    #pragma unroll 8
    for (int j = 0; j < 256; ++j)
        a = fmaf(s_row[j], wqt[j * 256 + t], a);
    qf_g[((size_t)b * 8 + qi) * 256 + t] = a;
}

// slotprep phase B: grid (32 b, 4 h). wkq fold + c0/c1 + wp_bf write.
__global__ __launch_bounds__(256) void k_prep_b(
    const float* __restrict__ qf_g, const float* __restrict__ Wk,
    const float* __restrict__ g_in, const float* __restrict__ b_in,
    unsigned short* __restrict__ wp_bf, float* __restrict__ c0_g, float* __restrict__ c1_g)
{
    __shared__ float qs[512];
    __shared__ float redc[4096];
    const int t = threadIdx.x;
    const int b = blockIdx.x, h = blockIdx.y;
    const int lane = t & 63, w = t >> 6;
    const float LNS = 0.125f * 1.44269504f;

    #pragma unroll
    for (int rep = 0; rep < 2; ++rep) {
        int idx = rep * 256 + t;
        int qi = idx >> 6, d = idx & 63;
        qs[idx] = qf_g[((size_t)b * 8 + qi) * 256 + h * 64 + d];
    }
    __syncthreads();

    float a2[8];
    #pragma unroll
    for (int qi = 0; qi < 8; ++qi) a2[qi] = 0.f;
    #pragma unroll 4
    for (int d = 0; d < 64; ++d) {
        float wv = Wk[(size_t)(h * 64 + d) * 256 + t];
        #pragma unroll
        for (int qi = 0; qi < 8; ++qi) a2[qi] = fmaf(qs[qi * 64 + d], wv, a2[qi]);
    }
    const float gv = g_in[t], bv = b_in[t];
    #pragma unroll
    for (int qi = 0; qi < 8; ++qi) {
        float kv = LNS * a2[qi];
        float we = kv * gv;
        wp_bf[((size_t)b * HQN + h * 8 + qi) * 256 + t] = (unsigned short)bfr(we);
        redc[qi * 256 + t] = we;
        redc[2048 + qi * 256 + t] = kv * bv;
    }
    __syncthreads();
    #pragma unroll
    for (int rep = 0; rep < 2; ++rep) {
        int r = w * 2 + rep;
        float sv1 = redc[r * 256 + lane] + redc[r * 256 + 64 + lane] +
                    redc[r * 256 + 128 + lane] + redc[r * 256 + 192 + lane];
        float sv0 = redc[2048 + r * 256 + lane] + redc[2048 + r * 256 + 64 + lane] +
                    redc[2048 + r * 256 + 128 + lane] + redc[2048 + r * 256 + 192 + lane];
        #pragma unroll
        for (int o = 32; o >= 1; o >>= 1) {
            sv1 += __shfl_xor(sv1, o, 64);
            sv0 += __shfl_xor(sv0, o, 64);
        }
        if (lane == 0) {
            c1_g[b * 32 + h * 8 + r] = sv1;
            c0_g[b * 32 + h * 8 + r] = sv0;
        }
    }
}

// ---------------------------------------------------------------------------
// k_attn helpers
__device__ __forceinline__ void load_x(const float* __restrict__ inp, int b, int n0,
                                       int tok_s, int seg8, float4* ld) {
    const float4* row4 = (const float4*)(inp + ((size_t)b * NKV + n0 + tok_s) * 256);
    #pragma unroll
    for (int u = 0; u < 8; ++u) ld[u] = row4[(u >> 2) * 32 + seg8 * 4 + (u & 3)];
}

__device__ __forceinline__ void pack_x(const float4* ld, char* dst, int tok_s, int seg8) {
    #pragma unroll
    for (int c = 0; c < 2; ++c) {
        int nt = seg8 + 8 * c;
        #pragma unroll
        for (int h = 0; h < 2; ++h) {
            float4 fa = ld[c * 4 + h * 2], fb = ld[c * 4 + h * 2 + 1];
            uint4 pk;
            pk.x = pk2(fa.x, fa.y); pk.y = pk2(fa.z, fa.w);
            pk.z = pk2(fb.x, fb.y); pk.w = pk2(fb.z, fb.w);
            *(uint4*)(dst + nt * 1040 + tok_s * 32 + h * 16) = pk;
        }
    }
}

__device__ __forceinline__ void calc_stats(const float4* ld, float* sb,
                                           float* __restrict__ rs_g, float* __restrict__ rm_g,
                                           int b, int n0, int tok_s, int seg8) {
    float s0 = 0.f, s1 = 0.f;
    #pragma unroll
    for (int u = 0; u < 8; ++u) {
        float4 v = ld[u];
        s0 += v.x + v.y + v.z + v.w;
        s1 = fmaf(v.x, v.x, s1); s1 = fmaf(v.y, v.y, s1);
        s1 = fmaf(v.z, v.z, s1); s1 = fmaf(v.w, v.w, s1);
    }
    s0 += __shfl_xor(s0, 1, 64); s1 += __shfl_xor(s1, 1, 64);
    s0 += __shfl_xor(s0, 2, 64); s1 += __shfl_xor(s1, 2, 64);
    s0 += __shfl_xor(s0, 4, 64); s1 += __shfl_xor(s1, 4, 64);
    float m  = s0 * (1.f / 256.f);
    float rs = rsqrtf(s1 * (1.f / 256.f) - m * m + 1e-5f);
    if (seg8 == 0) {
        sb[tok_s] = rs;
        sb[32 + tok_s] = rs * m;
        rs_g[b * 4096 + n0 + tok_s] = rs;
        rm_g[b * 4096 + n0 + tok_s] = rs * m;
    }
}

// ---------------------------------------------------------------------------
// Main fused MFMA pass. 1024 blocks, 4 chunks of 32 tokens, double-buffered xb.
// Next-chunk loads issued at chunk top (pinned); packed into other buffer after
// barrier D. V partials: plain stores to Vpart (reduced by k_vred, no atomics).
template<int STATS, int WVIS>
__global__ __launch_bounds__(256) void k_attn(
    const float* __restrict__ inp, const unsigned short* __restrict__ wp_bf,
    const float* __restrict__ c0_g, const float* __restrict__ c1_g,
    float* __restrict__ vpart, float* __restrict__ A0_g, float* __restrict__ A1_g,
    float* __restrict__ rs_g, float* __restrict__ rm_g,
    float* __restrict__ out_vis, float* __restrict__ out_temp)
{
    __shared__ unsigned short xb[2][8320];      // 2 x 16640 B double buffer
    __shared__ unsigned short wl[8192];         // [hq][k] swizzled
    __shared__ unsigned short pt[1024];         // [hq][tok] swizzled bf16 P (= a*rs)
    __shared__ float stats[2][64];              // [0..32): rs, [32..64): rm
    __shared__ float redm[64];
    __shared__ float reds[64];

    const int t = threadIdx.x;
    const int l = t & 63, w = t >> 6;
    const int g = l >> 4, li = l & 15;
    const int b = blockIdx.y, kb = blockIdx.x;

    char* xbB = (char*)xb;
    char* wlB = (char*)wl;
    char* ptB = (char*)pt;
    const int tok_s = t >> 3, seg8 = t & 7;
    const int cbase = kb * 4;

    // stage W'' into LDS (swizzled rows [hq][k])
    {
        const uint4* wp4 = (const uint4*)wp_bf + ((size_t)b * 8192 + (t >> 3) * 256 + (t & 7) * 32) / 8;
        const int hq = t >> 3, sg = t & 7;
        #pragma unroll
        for (int q = 0; q < 4; ++q) {
            uint4 v = wp4[q];
            *(uint4*)(wlB + hq * 512 + (((sg * 4 + q) ^ (hq & 7)) * 16)) = v;
        }
    }

    const int Mt = w & 1, Nt = w >> 1;
    const int hqB = Nt * 16 + li;
    const float c0r = c0_g[b * 32 + hqB];
    const float c1r = c1_g[b * 32 + hqB];
    const int MtV = w >> 1, ntb = (w & 1) * 8;
    const int hqA = MtV * 16 + li;

    f32x4 av[8];
    #pragma unroll
    for (int u = 0; u < 8; ++u) av[u] = (f32x4){0.f, 0.f, 0.f, 0.f};
    float A0acc = 0.f, A1acc = 0.f;

    const unsigned xbase = (unsigned)(uintptr_t)xbB;

    // ---- prologue: chunk 0 into buffer 0 ----
    {
        float4 ldA[8];
        load_x(inp, b, cbase * 32, tok_s, seg8, ldA);
        if (STATS) {
            calc_stats(ldA, &stats[0][0], rs_g, rm_g, b, cbase * 32, tok_s, seg8);
        } else {
            if (t < 32) stats[0][t] = rs_g[b * 4096 + cbase * 32 + t];
            else if (t < 64) stats[0][t] = rm_g[b * 4096 + cbase * 32 + t - 32];
        }
        pack_x(ldA, xbB, tok_s, seg8);
    }
    __syncthreads();

    #pragma unroll
    for (int ci = 0; ci < 4; ++ci) {
        const int cur = ci & 1, nxt = cur ^ 1;
        const int n0 = (cbase + ci) * 32;
        char* xc = xbB + cur * 16640;
        char* xn = xbB + nxt * 16640;

        // ---- issue next-chunk loads (latency hidden under this chunk) ----
        float4 ldN[8];
        if (ci < 3) load_x(inp, b, n0 + 32, tok_s, seg8, ldN);
        __builtin_amdgcn_sched_barrier(0);

        // ---- S = X * W''^T (raw-x accumulate) ----
        f32x4 accS = (f32x4){0.f, 0.f, 0.f, 0.f};
        #pragma unroll
        for (int kk = 0; kk < 8; ++kk) {
            s16x8 af = *(const s16x8*)(xc + (kk * 2 + (g >> 1)) * 1040 +
                                       (Mt * 16 + li) * 32 + (g & 1) * 16);
            s16x8 bf = *(const s16x8*)(wlB + hqB * 512 + (((kk * 4 + g) ^ (hqB & 7)) * 16));
            accS = __builtin_amdgcn_mfma_f32_16x16x32_bf16(af, bf, accS, 0, 0, 0);
        }

        // ---- logits + merged-barrier joint softmax over 32 hq ----
        float lg[4], rsv[4], rmv[4], mh[4], ex[4], aa[4];
        #pragma unroll
        for (int r = 0; r < 4; ++r) {
            int tokr = Mt * 16 + g * 4 + r;
            rsv[r] = stats[cur][tokr];
            rmv[r] = stats[cur][32 + tokr];
            lg[r] = fmaf(rsv[r], accS[r], fmaf(-rmv[r], c1r, c0r));
        }
        #pragma unroll
        for (int r = 0; r < 4; ++r) {
            float v = lg[r];
            v = fmaxf(v, __shfl_xor(v, 1, 64));
            v = fmaxf(v, __shfl_xor(v, 2, 64));
            v = fmaxf(v, __shfl_xor(v, 4, 64));
            v = fmaxf(v, __shfl_xor(v, 8, 64));
            mh[r] = v;
            ex[r] = exp2f(lg[r] - v);
            float s = ex[r];
            s += __shfl_xor(s, 1, 64);
            s += __shfl_xor(s, 2, 64);
            s += __shfl_xor(s, 4, 64);
            s += __shfl_xor(s, 8, 64);
            if (li == 0) {
                int tokr = Mt * 16 + g * 4 + r;
                redm[tokr * 2 + Nt] = v;
                reds[tokr * 2 + Nt] = s;
            }
        }
        __syncthreads();   // B
        #pragma unroll
        for (int r = 0; r < 4; ++r) {
            int tokr = Mt * 16 + g * 4 + r;
            float m0 = redm[tokr * 2], m1 = redm[tokr * 2 + 1];
            float mx = fmaxf(m0, m1);
            float tot = reds[tokr * 2] * exp2f(m0 - mx) + reds[tokr * 2 + 1] * exp2f(m1 - mx);
            aa[r] = ex[r] * (exp2f(mh[r] - mx) / tot);
            A0acc += aa[r];
            A1acc = fmaf(aa[r], rmv[r], A1acc);
        }
        {
            uint2 pw;
            pw.x = pk2(aa[0] * rsv[0], aa[1] * rsv[1]);
            pw.y = pk2(aa[2] * rsv[2], aa[3] * rsv[3]);
            int tokb = Mt * 16 + g * 4;
            int slot = (tokb >> 3) ^ ((hqB >> 1) & 3);
            *(uint2*)(ptB + hqB * 64 + slot * 16 + (tokb & 7) * 2) = pw;
        }
        __syncthreads();   // D: P ready

        if (WVIS) {
            int tk = t >> 3, q = t & 7;
            float sv = 0.f;
            #pragma unroll
            for (int h = 0; h < 4; ++h) {
                int hq = h * 8 + q;
                int slot = (tk >> 3) ^ ((hq >> 1) & 3);
                sv += bf2f(*(const unsigned short*)(ptB + hq * 64 + slot * 16 + (tk & 7) * 2));
            }
            float vv = sv / stats[cur][tk];
            size_t o = ((size_t)b * NKV + n0 + tk) * 8 + q;
            out_vis[o] = vv; out_temp[o] = vv;
        }

        // ---- pack next chunk into other buffer (loads have landed by now) ----
        if (ci < 3) {
            if (STATS) {
                calc_stats(ldN, &stats[nxt][0], rs_g, rm_g, b, n0 + 32, tok_s, seg8);
            } else {
                if (t < 32) stats[nxt][t] = rs_g[b * 4096 + n0 + 32 + t];
                else if (t < 64) stats[nxt][t] = rm_g[b * 4096 + n0 + 32 + t - 32];
            }
            pack_x(ldN, xn, tok_s, seg8);
        }

        // ---- V += P^T(A) * X(B) via tr-reads ----
        {
            s16x8 pa = *(const s16x8*)(ptB + hqA * 64 + ((g ^ ((hqA >> 1) & 3)) * 16));
            unsigned abase = xbase + cur * 16640 + g * 256 + li * 8;
            v2i t0a = tr_read(abase + (ntb + 0) * 1040);
            v2i t0b = tr_read(abase + (ntb + 0) * 1040 + 128);
            v2i t1a = tr_read(abase + (ntb + 1) * 1040);
            v2i t1b = tr_read(abase + (ntb + 1) * 1040 + 128);
            v2i t2a = tr_read(abase + (ntb + 2) * 1040);
            v2i t2b = tr_read(abase + (ntb + 2) * 1040 + 128);
            v2i t3a = tr_read(abase + (ntb + 3) * 1040);
            v2i t3b = tr_read(abase + (ntb + 3) * 1040 + 128);
            asm volatile("s_waitcnt lgkmcnt(0)" ::: "memory");
            __builtin_amdgcn_sched_barrier(0);
            av[0] = __builtin_amdgcn_mfma_f32_16x16x32_bf16(pa, mk_frag(t0a, t0b), av[0], 0, 0, 0);
            av[1] = __builtin_amdgcn_mfma_f32_16x16x32_bf16(pa, mk_frag(t1a, t1b), av[1], 0, 0, 0);
            av[2] = __builtin_amdgcn_mfma_f32_16x16x32_bf16(pa, mk_frag(t2a, t2b), av[2], 0, 0, 0);
            av[3] = __builtin_amdgcn_mfma_f32_16x16x32_bf16(pa, mk_frag(t3a, t3b), av[3], 0, 0, 0);
            v2i t4a = tr_read(abase + (ntb + 4) * 1040);
            v2i t4b = tr_read(abase + (ntb + 4) * 1040 + 128);
            v2i t5a = tr_read(abase + (ntb + 5) * 1040);
            v2i t5b = tr_read(abase + (ntb + 5) * 1040 + 128);
            v2i t6a = tr_read(abase + (ntb + 6) * 1040);
            v2i t6b = tr_read(abase + (ntb + 6) * 1040 + 128);
            v2i t7a = tr_read(abase + (ntb + 7) * 1040);
            v2i t7b = tr_read(abase + (ntb + 7) * 1040 + 128);
            asm volatile("s_waitcnt lgkmcnt(0)" ::: "memory");
            __builtin_amdgcn_sched_barrier(0);
            av[4] = __builtin_amdgcn_mfma_f32_16x16x32_bf16(pa, mk_frag(t4a, t4b), av[4], 0, 0, 0);
            av[5] = __builtin_amdgcn_mfma_f32_16x16x32_bf16(pa, mk_frag(t5a, t5b), av[5], 0, 0, 0);
            av[6] = __builtin_amdgcn_mfma_f32_16x16x32_bf16(pa, mk_frag(t6a, t6b), av[6], 0, 0, 0);
            av[7] = __builtin_amdgcn_mfma_f32_16x16x32_bf16(pa, mk_frag(t7a, t7b), av[7], 0, 0, 0);
        }
        __syncthreads();   // E: xb[nxt]/stats[nxt] visible; xb[cur]/pt free
    }

    // ---- final accumulation: A0/A1 atomic (tiny), V plain partial stores ----
    A0acc += __shfl_xor(A0acc, 16, 64); A0acc += __shfl_xor(A0acc, 32, 64);
    A1acc += __shfl_xor(A1acc, 16, 64); A1acc += __shfl_xor(A1acc, 32, 64);
    if (g == 0) {
        atomicAdd(A0_g + b * 32 + hqB, A0acc);
        atomicAdd(A1_g + b * 32 + hqB, A1acc);
    }
    float* vp = vpart + ((size_t)(b * 32 + kb) * 32) * 256;
    #pragma unroll
    for (int i = 0; i < 8; ++i) {
        int j = (ntb + i) * 16 + li;
        #pragma unroll
        for (int r = 0; r < 4; ++r) {
            int hq = MtV * 16 + g * 4 + r;
            vp[(size_t)hq * 256 + j] = av[i][r];
        }
    }
}

// ---------------------------------------------------------------------------
// V reduction: V[b][hq][j] = sum_kb Vpart[b*32+kb][hq][j].  grid (32, 32).
__global__ __launch_bounds__(256) void k_vred(
    const float* __restrict__ vpart, float* __restrict__ V_g)
{
    const int t = threadIdx.x;
    const int b = blockIdx.x, hq = blockIdx.y;
    const float* p = vpart + ((size_t)(b * 32) * 32 + hq) * 256 + t;
    float s = 0.f;
    #pragma unroll 8
    for (int kb = 0; kb < 32; ++kb)
        s += p[(size_t)kb * 8192];
    V_g[((size_t)b * 32 + hq) * 256 + t] = s;
}

// ---------------------------------------------------------------------------
// gx | gh GEMMs. grid (6, 64). chunk-0 blocks also zero slot_nxt rows.
__global__ __launch_bounds__(256) void k_gates(
    const float* __restrict__ V_g, const float* __restrict__ A0_g,
    const float* __restrict__ A1_g,
    const float* __restrict__ g_in, const float* __restrict__ b_in,
    const float* __restrict__ slot_cur,
    const unsigned* __restrict__ WfT2, const unsigned* __restrict__ WhhT2,
    float* __restrict__ gxh, float* __restrict__ slot_nxt)
{
    __shared__ __align__(16) float aT[1024 * 4];   // [k][rr]
    const int t = threadIdx.x;
    const int rg = blockIdx.y;
    const int chunk = blockIdx.x;
    const int row0 = rg * 4;
    float acc0 = 0.f, acc1 = 0.f, acc2 = 0.f, acc3 = 0.f;

    if (chunk == 0) {
        #pragma unroll
        for (int rr = 0; rr < 4; ++rr)
            slot_nxt[(size_t)(row0 + rr) * 256 + t] = 0.f;
    }

    if (chunk < 3) {
        const int b = rg >> 1, qi0 = (rg & 1) * 4;
        const float gt = g_in[t], bt = b_in[t];
        #pragma unroll
        for (int kk = 0; kk < 4; ++kk) {
            float4 y4;
            #pragma unroll
            for (int rr = 0; rr < 4; ++rr) {
                int hq = kk * 8 + qi0 + rr;
                float A0 = A0_g[b * 32 + hq], A1 = A1_g[b * 32 + hq];
                float den = A0 + EPSR * (float)NKV;
                float vv = V_g[((size_t)b * 32 + hq) * 256 + t];
                float yv = (gt * (vv - A1) + bt * A0) / den;
                ((float*)&y4)[rr] = yv;
            }
            *(float4*)(aT + (kk * 256 + t) * 4) = y4;
        }
        __syncthreads();
        const unsigned* wp = WfT2 + chunk * 256 + t;
        #pragma unroll 4
        for (int k2 = 0; k2 < 512; ++k2) {
            unsigned wv = wp[(size_t)k2 * 768];
            float w0 = bflo(wv), w1 = bfhi(wv);
            float4 a0 = *(const float4*)(aT + 8 * k2);
            float4 a1 = *(const float4*)(aT + 8 * k2 + 4);
            acc0 = fmaf(a0.x, w0, acc0); acc0 = fmaf(a1.x, w1, acc0);
            acc1 = fmaf(a0.y, w0, acc1); acc1 = fmaf(a1.y, w1, acc1);
            acc2 = fmaf(a0.z, w0, acc2); acc2 = fmaf(a1.z, w1, acc2);
            acc3 = fmaf(a0.w, w0, acc3); acc3 = fmaf(a1.w, w1, acc3);
        }
        float* go = gxh + (size_t)row0 * 1536 + chunk * 256 + t;
        go[0] = acc0; go[1536] = acc1; go[3072] = acc2; go[4608] = acc3;
    } else {
        const int gc = chunk - 3;
        {
            float4 y4;
            #pragma unroll
            for (int rr = 0; rr < 4; ++rr)
                ((float*)&y4)[rr] = slot_cur[(size_t)(row0 + rr) * 256 + t];
            *(float4*)(aT + t * 4) = y4;
        }
        __syncthreads();
        const unsigned* wp = WhhT2 + gc * 256 + t;
        #pragma unroll 4
        for (int k2 = 0; k2 < 128; ++k2) {
            unsigned wv = wp[(size_t)k2 * 768];
            float w0 = bflo(wv), w1 = bfhi(wv);
            float4 a0 = *(const float4*)(aT + 8 * k2);
            float4 a1 = *(const float4*)(aT + 8 * k2 + 4);
            acc0 = fmaf(a0.x, w0, acc0); acc0 = fmaf(a1.x, w1, acc0);
            acc1 = fmaf(a0.y, w0, acc1); acc1 = fmaf(a1.y, w1, acc1);
            acc2 = fmaf(a0.z, w0, acc2); acc2 = fmaf(a1.z, w1, acc2);
            acc3 = fmaf(a0.w, w0, acc3); acc3 = fmaf(a1.w, w1, acc3);
        }
        float* go = gxh + (size_t)row0 * 1536 + 768 + gc * 256 + t;
        go[0] = acc0; go[1536] = acc1; go[3072] = acc2; go[4608] = acc3;
    }
}

// ---------------------------------------------------------------------------
// Fused GRU elementwise + LN + MLP(W1,relu,W2) with h1 in LDS. grid (4, 64).
__global__ __launch_bounds__(256) void k_mlp(
    const float* __restrict__ gxh, const float* __restrict__ slot_cur,
    const float* __restrict__ bih, const float* __restrict__ bhh,
    const float* __restrict__ gm, const float* __restrict__ bm,
    const unsigned* __restrict__ W1T2, const float* __restrict__ b1,
    const unsigned* __restrict__ W2T2, const float* __restrict__ b2,
    float* __restrict__ slot_nxt)
{
    __shared__ __align__(16) float mT[1024];
    __shared__ float sm_l[4][256];
    __shared__ float h1_l[4][256];
    __shared__ float lnst[8];
    const int t = threadIdx.x;
    const int rg = blockIdx.y, chunk = blockIdx.x;
    const int row0 = rg * 4;
    const int lane = t & 63, w = t >> 6;

    const float bi0 = bih[t], bi1 = bih[256 + t], bi2 = bih[512 + t];
    const float bh0 = bhh[t], bh1 = bhh[256 + t], bh2 = bhh[512 + t];
    float smid[4];
    #pragma unroll
    for (int rr = 0; rr < 4; ++rr) {
        const float* gr = gxh + (size_t)(row0 + rr) * 1536;
        float gx0 = gr[t], gx1 = gr[256 + t], gx2 = gr[512 + t];
        float gh0 = gr[768 + t], gh1 = gr[1024 + t], gh2 = gr[1280 + t];
        float spv = slot_cur[(size_t)(row0 + rr) * 256 + t];
        float r = 1.f / (1.f + __expf(-(gx0 + bi0 + gh0 + bh0)));
        float z = 1.f / (1.f + __expf(-(gx1 + bi1 + gh1 + bh1)));
        float n = tanhf(gx2 + bi2 + r * (gh2 + bh2));
        smid[rr] = (1.f - z) * n + z * spv;
        sm_l[rr][t] = smid[rr];
    }
    __syncthreads();
    {
        float4 v = *(const float4*)(&sm_l[w][lane * 4]);
        float s0 = v.x + v.y + v.z + v.w;
        float s1 = v.x * v.x + v.y * v.y + v.z * v.z + v.w * v.w;
        #pragma unroll
        for (int o = 32; o >= 1; o >>= 1) { s0 += __shfl_xor(s0, o, 64); s1 += __shfl_xor(s1, o, 64); }
        if (lane == 0) {
            float mu = s0 * (1.f / 256.f);
            lnst[w * 2] = mu;
            lnst[w * 2 + 1] = rsqrtf(s1 * (1.f / 256.f) - mu * mu + 1e-5f);
        }
    }
    __syncthreads();
    {
        const float gmt = gm[t], bmt = bm[t];
        float4 m4;
        #pragma unroll
        for (int rr = 0; rr < 4; ++rr)
            ((float*)&m4)[rr] = (smid[rr] - lnst[rr * 2]) * lnst[rr * 2 + 1] * gmt + bmt;
        *(float4*)(mT + t * 4) = m4;
    }
    __syncthreads();

    {
        float acc0 = 0.f, acc1 = 0.f, acc2 = 0.f, acc3 = 0.f;
        const unsigned* wp = W1T2 + chunk * 256 + t;
        #pragma unroll 4
        for (int k2 = 0; k2 < 128; ++k2) {
            unsigned wv = wp[(size_t)k2 * 1024];
            float w0 = bflo(wv), w1 = bfhi(wv);
            float4 a0 = *(const float4*)(mT + 8 * k2);
            float4 a1 = *(const float4*)(mT + 8 * k2 + 4);
            acc0 = fmaf(a0.x, w0, acc0); acc0 = fmaf(a1.x, w1, acc0);
            acc1 = fmaf(a0.y, w0, acc1); acc1 = fmaf(a1.y, w1, acc1);
            acc2 = fmaf(a0.z, w0, acc2); acc2 = fmaf(a1.z, w1, acc2);
            acc3 = fmaf(a0.w, w0, acc3); acc3 = fmaf(a1.w, w1, acc3);
        }
        const float b1t = b1[chunk * 256 + t];
        h1_l[0][t] = fmaxf(acc0 + b1t, 0.f);
        h1_l[1][t] = fmaxf(acc1 + b1t, 0.f);
        h1_l[2][t] = fmaxf(acc2 + b1t, 0.f);
        h1_l[3][t] = fmaxf(acc3 + b1t, 0.f);
    }
    __syncthreads();

    {
        float o0 = 0.f, o1 = 0.f, o2 = 0.f, o3 = 0.f;
        const unsigned* wp = W2T2 + (size_t)(chunk * 128) * 256 + t;
        #pragma unroll 4
        for (int k2 = 0; k2 < 128; ++k2) {
            unsigned wv = wp[(size_t)k2 * 256];
            float w0 = bflo(wv), w1 = bfhi(wv);
            float a00 = h1_l[0][2 * k2], a01 = h1_l[0][2 * k2 + 1];
            float a10 = h1_l[1][2 * k2], a11 = h1_l[1][2 * k2 + 1];
            float a20 = h1_l[2][2 * k2], a21 = h1_l[2][2 * k2 + 1];
            float a30 = h1_l[3][2 * k2], a31 = h1_l[3][2 * k2 + 1];
            o0 = fmaf(a00, w0, o0); o0 = fmaf(a01, w1, o0);
            o1 = fmaf(a10, w0, o1); o1 = fmaf(a11, w1, o1);
            o2 = fmaf(a20, w0, o2); o2 = fmaf(a21, w1, o2);
            o3 = fmaf(a30, w0, o3); o3 = fmaf(a31, w1, o3);
        }
        const float b2t = b2[t];
        float base0 = (chunk == 0) ? smid[0] + b2t : 0.f;
        float base1 = (chunk == 0) ? smid[1] + b2t : 0.f;
        float base2 = (chunk == 0) ? smid[2] + b2t : 0.f;
        float base3 = (chunk == 0) ? smid[3] + b2t : 0.f;
        atomicAdd(slot_nxt + (size_t)(row0 + 0) * 256 + t, o0 + base0);
        atomicAdd(slot_nxt + (size_t)(row0 + 1) * 256 + t, o1 + base1);
        atomicAdd(slot_nxt + (size_t)(row0 + 2) * 256 + t, o2 + base2);
        atomicAdd(slot_nxt + (size_t)(row0 + 3) * 256 + t, o3 + base3);
    }
}

// ---------------------------------------------------------------------------
extern "C" void kernel_launch(void* const* d_in, const int* in_sizes, int n_in,
                              void* d_out, int out_size, void* d_ws, size_t ws_size,
                              hipStream_t stream) {
    const float* inp     = (const float*)d_in[0];
    const float* slots0  = (const float*)d_in[1];
    const float* ln_in_g = (const float*)d_in[2];
    const float* ln_in_b = (const float*)d_in[3];
    const float* ln_s_g  = (const float*)d_in[4];
    const float* ln_s_b  = (const float*)d_in[5];
    const float* ln_m_g  = (const float*)d_in[6];
    const float* ln_m_b  = (const float*)d_in[7];
    const float* Wq  = (const float*)d_in[8];
    const float* Wk  = (const float*)d_in[9];
    const float* Wv  = (const float*)d_in[10];
    const float* Wih = (const float*)d_in[11];
    const float* Whh = (const float*)d_in[12];
    const float* bih = (const float*)d_in[13];
    const float* bhh = (const float*)d_in[14];
    const float* W1  = (const float*)d_in[15];
    const float* b1  = (const float*)d_in[16];
    const float* W2  = (const float*)d_in[17];
    const float* b2  = (const float*)d_in[18];

    float* ws = (float*)d_ws;
    float* V_g   = ws + WS_V;
    float* A0_g  = ws + WS_A0;
    float* A1_g  = ws + WS_A1;
    float* c0_g  = ws + WS_C0;
    float* c1_g  = ws + WS_C1;
    float* slotA = ws + WS_SLOTA;
    float* slotB = ws + WS_SLOTB;
    float* wqt   = ws + WS_WQT;
    float* qf_g  = ws + WS_QF;
    float* gxh   = ws + WS_WPGXH;    // aliased with wp_bf (disjoint lifetimes)
    unsigned short* wp_bf = (unsigned short*)(ws + WS_WPGXH);
    unsigned* WfT2  = (unsigned*)(ws + WS_WFT);
    unsigned* WhhT2 = (unsigned*)(ws + WS_WHHT);
    unsigned* W1T2  = (unsigned*)(ws + WS_W1T);
    unsigned* W2T2  = (unsigned*)(ws + WS_W2T);
    float* rs_g  = ws + WS_RS;
    float* rm_g  = ws + WS_RM;
    float* vpart = ws + WS_VPART;

    float* out_slots = (float*)d_out;
    float* out_vis   = out_slots + 32 * 8 * 256;
    float* out_temp  = out_vis + 32 * 4096 * 8;

    k_tr<<<dim3(8, 8), dim3(32, 8), 0, stream>>>(Wq, wqt, 256, 256);
    k_wfold<<<768, 256, 0, stream>>>(Wih, Wv, WfT2);
    k_trpack<<<128, 256, 0, stream>>>(Whh, WhhT2, 768, 256);
    k_trpack<<<128, 256, 0, stream>>>(W1, W1T2, 1024, 256);
    k_trpack<<<512, 256, 0, stream>>>(W2, W2T2, 256, 1024);
    k_copy<<<256, 256, 0, stream>>>(slots0, slotA, 65536);

    for (int it = 0; it < 3; ++it) {
        float* cur = (it & 1) ? slotB : slotA;
        float* nxt = (it & 1) ? slotA : slotB;
        k_prep_a<<<dim3(32, 8), 256, 0, stream>>>(cur, ln_s_g, ln_s_b, wqt, qf_g,
                                                  A0_g, A1_g);
        k_prep_b<<<dim3(32, 4), 256, 0, stream>>>(qf_g, Wk, ln_in_g, ln_in_b,
                                                  wp_bf, c0_g, c1_g);
        if (it == 0)
            k_attn<1, 0><<<dim3(32, 32), 256, 0, stream>>>(
                inp, wp_bf, c0_g, c1_g, vpart, A0_g, A1_g, rs_g, rm_g, out_vis, out_temp);
        else if (it == 1)
            k_attn<0, 0><<<dim3(32, 32), 256, 0, stream>>>(
                inp, wp_bf, c0_g, c1_g, vpart, A0_g, A1_g, rs_g, rm_g, out_vis, out_temp);
        else
            k_attn<0, 1><<<dim3(32, 32), 256, 0, stream>>>(
                inp, wp_bf, c0_g, c1_g, vpart, A0_g, A1_g, rs_g, rm_g, out_vis, out_temp);
        k_vred<<<dim3(32, 32), 256, 0, stream>>>(vpart, V_g);
        k_gates<<<dim3(6, 64), 256, 0, stream>>>(
            V_g, A0_g, A1_g, ln_in_g, ln_in_b, cur, WfT2, WhhT2, gxh, nxt);
        k_mlp<<<dim3(4, 64), 256, 0, stream>>>(
            gxh, cur, bih, bhh, ln_m_g, ln_m_b, W1T2, b1, W2T2, b2, nxt);
    }
    k_copy<<<256, 256, 0, stream>>>(slotB, out_slots, 65536);
}

// Round 10
// 474.264 us; speedup vs baseline: 1.1195x; 1.0042x over previous
//
#include <hip/hip_runtime.h>
#include <math.h>

// ---------------------------------------------------------------------------
// SlotAttention fused forward. MFMA (bf16) attention path.
//   xb holds RAW bf16 x (double-buffered);  logit = rs*dot(x,w'') - rm*c1 + c0
//   P = a*rs;  rs/rm iteration-invariant (iter0 computes+stores, iters 1-2 load)
//   V partials: plain stores to Vpart[b,kb,hq,j], reduced by k_vred (no atomics)
//   k_attn split NC chunks/block (NC=2 if ws fits 64MB Vpart, else NC=4).
//   y-fold: updates_pre[hq,j] = (g_j*(V - A1) + b_j*A0)/(A0 + eps*N)
//   GRU/MLP: gx = yflat @ Wfold^T (Wv folded into W_ih); k_gates + fused k_mlp.
// ---------------------------------------------------------------------------

#define NKV   4096
#define DD    256
#define HQN   32
#define EPSR  1e-8f

// workspace layout (float offsets)
#define WS_V      0                     // 262144
#define WS_A0     262144                // 1024
#define WS_A1     263168                // 1024
#define WS_C0     264192                // 1024
#define WS_C1     265216                // 1024
#define WS_SLOTA  266240                // 65536
#define WS_SLOTB  331776                // 65536
#define WS_WQT    397312                // 65536 fp32 Wq^T
#define WS_QF     462848                // 65536 fp32 qf[b][qi][256]
#define WS_WPGXH  528384                // 393216 (wp_bf 131072f | gxh [256][1536])
#define WS_WFT    921600                // 393216 uints: WfoldT2 [512][768]
#define WS_WHHT   1314816               // 98304 uints:  WhhT2   [128][768]
#define WS_W1T    1413120               // 131072 uints: W1T2    [128][1024]
#define WS_W2T    1544192               // 131072 uints: W2T2    [512][256]
#define WS_RS     1675264               // 131072 fp32 rs per token
#define WS_RM     1806336               // 131072 fp32 rm per token
#define WS_VPART  1937408               // Vpart[b*KBMAX+kb][32hq][256j]
// NC=4: Vpart 8388608 f (32MB)  -> need 41.3MB (proven)
// NC=2: Vpart 16777216 f (64MB) -> need 74.9MB (runtime-guarded)

typedef float f32x4 __attribute__((ext_vector_type(4)));
typedef short s16x8 __attribute__((ext_vector_type(8)));
typedef int   v2i   __attribute__((ext_vector_type(2)));

__device__ __forceinline__ unsigned bfr(float f) {
    unsigned u = __float_as_uint(f);
    return (u + 0x7fffu + ((u >> 16) & 1u)) >> 16;
}
__device__ __forceinline__ unsigned pk2(float lo, float hi) {
    return bfr(lo) | (bfr(hi) << 16);
}
__device__ __forceinline__ float bf2f(unsigned short us) {
    return __uint_as_float((unsigned)us << 16);
}
__device__ __forceinline__ float bflo(unsigned u) { return __uint_as_float(u << 16); }
__device__ __forceinline__ float bfhi(unsigned u) { return __uint_as_float(u & 0xffff0000u); }

__device__ __forceinline__ v2i tr_read(unsigned addr) {
    v2i d;
    asm volatile("ds_read_b64_tr_b16 %0, %1" : "=v"(d) : "v"(addr));
    return d;
}
__device__ __forceinline__ s16x8 mk_frag(v2i a, v2i b) {
    union { int i[4]; s16x8 s; } u;
    u.i[0] = a.x; u.i[1] = a.y; u.i[2] = b.x; u.i[3] = b.y;
    return u.s;
}

__global__ __launch_bounds__(256) void k_copy(const float* __restrict__ in,
                                              float* __restrict__ out, int n) {
    int i = blockIdx.x * 256 + threadIdx.x;
    if (i < n) out[i] = in[i];
}

// generic 32x32 tiled fp32 transpose: in[R][C] -> out[C][R]
__global__ __launch_bounds__(256) void k_tr(const float* __restrict__ in,
                                            float* __restrict__ out, int R, int C) {
    __shared__ float tile[32][33];
    int bx = blockIdx.x * 32, by = blockIdx.y * 32;
    int x = bx + threadIdx.x;
    for (int k = 0; k < 32; k += 8) {
        int y = by + threadIdx.y + k;
        if (x < C && y < R) tile[threadIdx.y + k][threadIdx.x] = in[(size_t)y * C + x];
    }
    __syncthreads();
    int r = by + threadIdx.x;
    for (int k = 0; k < 32; k += 8) {
        int c = bx + threadIdx.y + k;
        if (c < C && r < R) out[(size_t)c * R + r] = tile[threadIdx.x][threadIdx.y + k];
    }
}

// ---------------------------------------------------------------------------
// Wfold: one block per output row c.
__global__ __launch_bounds__(256) void k_wfold(
    const float* __restrict__ Wih, const float* __restrict__ Wv,
    unsigned* __restrict__ WfT2)
{
    __shared__ float wr[256];
    const int c = blockIdx.x, t = threadIdx.x;
    wr[t] = Wih[(size_t)c * 256 + t];
    __syncthreads();
    const float2* wv2 = (const float2*)Wv;
    #pragma unroll
    for (int pp = 0; pp < 2; ++pp) {
        int P = pp * 256 + t;
        int h = P >> 7, p = P & 127;
        float f0 = 0.f, f1 = 0.f;
        #pragma unroll 8
        for (int d = 0; d < 64; ++d) {
            float a = wr[h * 64 + d];
            float2 v = wv2[(size_t)(h * 64 + d) * 128 + p];
            f0 = fmaf(a, v.x, f0); f1 = fmaf(a, v.y, f1);
        }
        WfT2[(size_t)P * 768 + c] = pk2(f0, f1);
    }
}

// transpose+pack: in fp32 [R][C] -> out uint [C/2][R]
__global__ __launch_bounds__(256) void k_trpack(
    const float* __restrict__ in, unsigned* __restrict__ out, int R, int C)
{
    const int c2 = blockIdx.x;
    const int t = threadIdx.x;
    for (int q = 0; q < R / 256; ++q) {
        int r = q * 256 + t;
        out[(size_t)c2 * R + r] = pk2(in[(size_t)r * C + 2 * c2],
                                      in[(size_t)r * C + 2 * c2 + 1]);
    }
}

// ---------------------------------------------------------------------------
// slotprep phase A: grid (32 b, 8 qi). LN(slots row qi) + qf row-GEMM vs wqt.
__global__ __launch_bounds__(256) void k_prep_a(
    const float* __restrict__ slots, const float* __restrict__ g_s, const float* __restrict__ b_s,
    const float* __restrict__ wqt, float* __restrict__ qf_g,
    float* __restrict__ A0_g, float* __restrict__ A1_g)
{
    __shared__ float s_row[256];
    __shared__ float red[8];
    const int t = threadIdx.x;
    const int b = blockIdx.x, qi = blockIdx.y;
    const int lane = t & 63, w = t >> 6;

    if (t < 4) { A0_g[b * 32 + t * 8 + qi] = 0.f; A1_g[b * 32 + t * 8 + qi] = 0.f; }

    float v = slots[((size_t)b * 8 + qi) * 256 + t];
    float s0 = v, s1 = v * v;
    #pragma unroll
    for (int o = 32; o >= 1; o >>= 1) { s0 += __shfl_xor(s0, o, 64); s1 += __shfl_xor(s1, o, 64); }
    if (lane == 0) { red[w] = s0; red[4 + w] = s1; }
    __syncthreads();
    {
        float m = (red[0] + red[1] + red[2] + red[3]) * (1.f / 256.f);
        float q2 = (red[4] + red[5] + red[6] + red[7]) * (1.f / 256.f);
        float rs = rsqrtf(q2 - m * m + 1e-5f);
        s_row[t] = (v - m) * rs * g_s[t] + b_s[t];
    }
    __syncthreads();

    float a = 0.f;
    #pragma unroll 8
    for (int j = 0; j < 256; ++j)
        a = fmaf(s_row[j], wqt[j * 256 + t], a);
    qf_g[((size_t)b * 8 + qi) * 256 + t] = a;
}

// slotprep phase B: grid (32 b, 4 h). wkq fold + c0/c1 + wp_bf write.
__global__ __launch_bounds__(256) void k_prep_b(
    const float* __restrict__ qf_g, const float* __restrict__ Wk,
    const float* __restrict__ g_in, const float* __restrict__ b_in,
    unsigned short* __restrict__ wp_bf, float* __restrict__ c0_g, float* __restrict__ c1_g)
{
    __shared__ float qs[512];
    __shared__ float redc[4096];
    const int t = threadIdx.x;
    const int b = blockIdx.x, h = blockIdx.y;
    const int lane = t & 63, w = t >> 6;
    const float LNS = 0.125f * 1.44269504f;

    #pragma unroll
    for (int rep = 0; rep < 2; ++rep) {
        int idx = rep * 256 + t;
        int qi = idx >> 6, d = idx & 63;
        qs[idx] = qf_g[((size_t)b * 8 + qi) * 256 + h * 64 + d];
    }
    __syncthreads();

    float a2[8];
    #pragma unroll
    for (int qi = 0; qi < 8; ++qi) a2[qi] = 0.f;
    #pragma unroll 4
    for (int d = 0; d < 64; ++d) {
        float wv = Wk[(size_t)(h * 64 + d) * 256 + t];
        #pragma unroll
        for (int qi = 0; qi < 8; ++qi) a2[qi] = fmaf(qs[qi * 64 + d], wv, a2[qi]);
    }
    const float gv = g_in[t], bv = b_in[t];
    #pragma unroll
    for (int qi = 0; qi < 8; ++qi) {
        float kv = LNS * a2[qi];
        float we = kv * gv;
        wp_bf[((size_t)b * HQN + h * 8 + qi) * 256 + t] = (unsigned short)bfr(we);
        redc[qi * 256 + t] = we;
        redc[2048 + qi * 256 + t] = kv * bv;
    }
    __syncthreads();
    #pragma unroll
    for (int rep = 0; rep < 2; ++rep) {
        int r = w * 2 + rep;
        float sv1 = redc[r * 256 + lane] + redc[r * 256 + 64 + lane] +
                    redc[r * 256 + 128 + lane] + redc[r * 256 + 192 + lane];
        float sv0 = redc[2048 + r * 256 + lane] + redc[2048 + r * 256 + 64 + lane] +
                    redc[2048 + r * 256 + 128 + lane] + redc[2048 + r * 256 + 192 + lane];
        #pragma unroll
        for (int o = 32; o >= 1; o >>= 1) {
            sv1 += __shfl_xor(sv1, o, 64);
            sv0 += __shfl_xor(sv0, o, 64);
        }
        if (lane == 0) {
            c1_g[b * 32 + h * 8 + r] = sv1;
            c0_g[b * 32 + h * 8 + r] = sv0;
        }
    }
}

// ---------------------------------------------------------------------------
// k_attn helpers
__device__ __forceinline__ void load_x(const float* __restrict__ inp, int b, int n0,
                                       int tok_s, int seg8, float4* ld) {
    const float4* row4 = (const float4*)(inp + ((size_t)b * NKV + n0 + tok_s) * 256);
    #pragma unroll
    for (int u = 0; u < 8; ++u) ld[u] = row4[(u >> 2) * 32 + seg8 * 4 + (u & 3)];
}

__device__ __forceinline__ void pack_x(const float4* ld, char* dst, int tok_s, int seg8) {
    #pragma unroll
    for (int c = 0; c < 2; ++c) {
        int nt = seg8 + 8 * c;
        #pragma unroll
        for (int h = 0; h < 2; ++h) {
            float4 fa = ld[c * 4 + h * 2], fb = ld[c * 4 + h * 2 + 1];
            uint4 pk;
            pk.x = pk2(fa.x, fa.y); pk.y = pk2(fa.z, fa.w);
            pk.z = pk2(fb.x, fb.y); pk.w = pk2(fb.z, fb.w);
            *(uint4*)(dst + nt * 1040 + tok_s * 32 + h * 16) = pk;
        }
    }
}

__device__ __forceinline__ void calc_stats(const float4* ld, float* sb,
                                           float* __restrict__ rs_g, float* __restrict__ rm_g,
                                           int b, int n0, int tok_s, int seg8) {
    float s0 = 0.f, s1 = 0.f;
    #pragma unroll
    for (int u = 0; u < 8; ++u) {
        float4 v = ld[u];
        s0 += v.x + v.y + v.z + v.w;
        s1 = fmaf(v.x, v.x, s1); s1 = fmaf(v.y, v.y, s1);
        s1 = fmaf(v.z, v.z, s1); s1 = fmaf(v.w, v.w, s1);
    }
    s0 += __shfl_xor(s0, 1, 64); s1 += __shfl_xor(s1, 1, 64);
    s0 += __shfl_xor(s0, 2, 64); s1 += __shfl_xor(s1, 2, 64);
    s0 += __shfl_xor(s0, 4, 64); s1 += __shfl_xor(s1, 4, 64);
    float m  = s0 * (1.f / 256.f);
    float rs = rsqrtf(s1 * (1.f / 256.f) - m * m + 1e-5f);
    if (seg8 == 0) {
        sb[tok_s] = rs;
        sb[32 + tok_s] = rs * m;
        rs_g[b * 4096 + n0 + tok_s] = rs;
        rm_g[b * 4096 + n0 + tok_s] = rs * m;
    }
}

// ---------------------------------------------------------------------------
// Main fused MFMA pass. grid (128/NC, 32). NC chunks of 32 tokens per block,
// double-buffered xb, plain Vpart stores (reduced by k_vred).
template<int NC, int STATS, int WVIS>
__global__ __launch_bounds__(256) void k_attn(
    const float* __restrict__ inp, const unsigned short* __restrict__ wp_bf,
    const float* __restrict__ c0_g, const float* __restrict__ c1_g,
    float* __restrict__ vpart, float* __restrict__ A0_g, float* __restrict__ A1_g,
    float* __restrict__ rs_g, float* __restrict__ rm_g,
    float* __restrict__ out_vis, float* __restrict__ out_temp)
{
    constexpr int KBMAX = 128 / NC;
    __shared__ unsigned short xb[2][8320];      // 2 x 16640 B double buffer
    __shared__ unsigned short wl[8192];         // [hq][k] swizzled
    __shared__ unsigned short pt[1024];         // [hq][tok] swizzled bf16 P (= a*rs)
    __shared__ float stats[2][64];              // [0..32): rs, [32..64): rm
    __shared__ float redm[64];
    __shared__ float reds[64];

    const int t = threadIdx.x;
    const int l = t & 63, w = t >> 6;
    const int g = l >> 4, li = l & 15;
    const int b = blockIdx.y, kb = blockIdx.x;

    char* xbB = (char*)xb;
    char* wlB = (char*)wl;
    char* ptB = (char*)pt;
    const int tok_s = t >> 3, seg8 = t & 7;
    const int cbase = kb * NC;

    // stage W'' into LDS (swizzled rows [hq][k])
    {
        const uint4* wp4 = (const uint4*)wp_bf + ((size_t)b * 8192 + (t >> 3) * 256 + (t & 7) * 32) / 8;
        const int hq = t >> 3, sg = t & 7;
        #pragma unroll
        for (int q = 0; q < 4; ++q) {
            uint4 v = wp4[q];
            *(uint4*)(wlB + hq * 512 + (((sg * 4 + q) ^ (hq & 7)) * 16)) = v;
        }
    }

    const int Mt = w & 1, Nt = w >> 1;
    const int hqB = Nt * 16 + li;
    const float c0r = c0_g[b * 32 + hqB];
    const float c1r = c1_g[b * 32 + hqB];
    const int MtV = w >> 1, ntb = (w & 1) * 8;
    const int hqA = MtV * 16 + li;

    f32x4 av[8];
    #pragma unroll
    for (int u = 0; u < 8; ++u) av[u] = (f32x4){0.f, 0.f, 0.f, 0.f};
    float A0acc = 0.f, A1acc = 0.f;

    const unsigned xbase = (unsigned)(uintptr_t)xbB;

    // ---- prologue: chunk 0 into buffer 0 ----
    {
        float4 ldA[8];
        load_x(inp, b, cbase * 32, tok_s, seg8, ldA);
        if (STATS) {
            calc_stats(ldA, &stats[0][0], rs_g, rm_g, b, cbase * 32, tok_s, seg8);
        } else {
            if (t < 32) stats[0][t] = rs_g[b * 4096 + cbase * 32 + t];
            else if (t < 64) stats[0][t] = rm_g[b * 4096 + cbase * 32 + t - 32];
        }
        pack_x(ldA, xbB, tok_s, seg8);
    }
    __syncthreads();

    #pragma unroll
    for (int ci = 0; ci < NC; ++ci) {
        const int cur = ci & 1, nxt = cur ^ 1;
        const int n0 = (cbase + ci) * 32;
        char* xc = xbB + cur * 16640;
        char* xn = xbB + nxt * 16640;

        // ---- issue next-chunk loads (latency hidden under this chunk) ----
        float4 ldN[8];
        if (ci < NC - 1) load_x(inp, b, n0 + 32, tok_s, seg8, ldN);
        __builtin_amdgcn_sched_barrier(0);

        // ---- S = X * W''^T (raw-x accumulate) ----
        f32x4 accS = (f32x4){0.f, 0.f, 0.f, 0.f};
        #pragma unroll
        for (int kk = 0; kk < 8; ++kk) {
            s16x8 af = *(const s16x8*)(xc + (kk * 2 + (g >> 1)) * 1040 +
                                       (Mt * 16 + li) * 32 + (g & 1) * 16);
            s16x8 bf = *(const s16x8*)(wlB + hqB * 512 + (((kk * 4 + g) ^ (hqB & 7)) * 16));
            accS = __builtin_amdgcn_mfma_f32_16x16x32_bf16(af, bf, accS, 0, 0, 0);
        }

        // ---- logits + merged-barrier joint softmax over 32 hq ----
        float lg[4], rsv[4], rmv[4], mh[4], ex[4], aa[4];
        #pragma unroll
        for (int r = 0; r < 4; ++r) {
            int tokr = Mt * 16 + g * 4 + r;
            rsv[r] = stats[cur][tokr];
            rmv[r] = stats[cur][32 + tokr];
            lg[r] = fmaf(rsv[r], accS[r], fmaf(-rmv[r], c1r, c0r));
        }
        #pragma unroll
        for (int r = 0; r < 4; ++r) {
            float v = lg[r];
            v = fmaxf(v, __shfl_xor(v, 1, 64));
            v = fmaxf(v, __shfl_xor(v, 2, 64));
            v = fmaxf(v, __shfl_xor(v, 4, 64));
            v = fmaxf(v, __shfl_xor(v, 8, 64));
            mh[r] = v;
            ex[r] = exp2f(lg[r] - v);
            float s = ex[r];
            s += __shfl_xor(s, 1, 64);
            s += __shfl_xor(s, 2, 64);
            s += __shfl_xor(s, 4, 64);
            s += __shfl_xor(s, 8, 64);
            if (li == 0) {
                int tokr = Mt * 16 + g * 4 + r;
                redm[tokr * 2 + Nt] = v;
                reds[tokr * 2 + Nt] = s;
            }
        }
        __syncthreads();   // B
        #pragma unroll
        for (int r = 0; r < 4; ++r) {
            int tokr = Mt * 16 + g * 4 + r;
            float m0 = redm[tokr * 2], m1 = redm[tokr * 2 + 1];
            float mx = fmaxf(m0, m1);
            float tot = reds[tokr * 2] * exp2f(m0 - mx) + reds[tokr * 2 + 1] * exp2f(m1 - mx);
            aa[r] = ex[r] * (exp2f(mh[r] - mx) / tot);
            A0acc += aa[r];
            A1acc = fmaf(aa[r], rmv[r], A1acc);
        }
        {
            uint2 pw;
            pw.x = pk2(aa[0] * rsv[0], aa[1] * rsv[1]);
            pw.y = pk2(aa[2] * rsv[2], aa[3] * rsv[3]);
            int tokb = Mt * 16 + g * 4;
            int slot = (tokb >> 3) ^ ((hqB >> 1) & 3);
            *(uint2*)(ptB + hqB * 64 + slot * 16 + (tokb & 7) * 2) = pw;
        }
        __syncthreads();   // D: P ready

        if (WVIS) {
            int tk = t >> 3, q = t & 7;
            float sv = 0.f;
            #pragma unroll
            for (int h = 0; h < 4; ++h) {
                int hq = h * 8 + q;
                int slot = (tk >> 3) ^ ((hq >> 1) & 3);
                sv += bf2f(*(const unsigned short*)(ptB + hq * 64 + slot * 16 + (tk & 7) * 2));
            }
            float vv = sv / stats[cur][tk];
            size_t o = ((size_t)b * NKV + n0 + tk) * 8 + q;
            out_vis[o] = vv; out_temp[o] = vv;
        }

        // ---- pack next chunk into other buffer (loads have landed by now) ----
        if (ci < NC - 1) {
            if (STATS) {
                calc_stats(ldN, &stats[nxt][0], rs_g, rm_g, b, n0 + 32, tok_s, seg8);
            } else {
                if (t < 32) stats[nxt][t] = rs_g[b * 4096 + n0 + 32 + t];
                else if (t < 64) stats[nxt][t] = rm_g[b * 4096 + n0 + 32 + t - 32];
            }
            pack_x(ldN, xn, tok_s, seg8);
        }

        // ---- V += P^T(A) * X(B) via tr-reads ----
        {
            s16x8 pa = *(const s16x8*)(ptB + hqA * 64 + ((g ^ ((hqA >> 1) & 3)) * 16));
            unsigned abase = xbase + cur * 16640 + g * 256 + li * 8;
            v2i t0a = tr_read(abase + (ntb + 0) * 1040);
            v2i t0b = tr_read(abase + (ntb + 0) * 1040 + 128);
            v2i t1a = tr_read(abase + (ntb + 1) * 1040);
            v2i t1b = tr_read(abase + (ntb + 1) * 1040 + 128);
            v2i t2a = tr_read(abase + (ntb + 2) * 1040);
            v2i t2b = tr_read(abase + (ntb + 2) * 1040 + 128);
            v2i t3a = tr_read(abase + (ntb + 3) * 1040);
            v2i t3b = tr_read(abase + (ntb + 3) * 1040 + 128);
            asm volatile("s_waitcnt lgkmcnt(0)" ::: "memory");
            __builtin_amdgcn_sched_barrier(0);
            av[0] = __builtin_amdgcn_mfma_f32_16x16x32_bf16(pa, mk_frag(t0a, t0b), av[0], 0, 0, 0);
            av[1] = __builtin_amdgcn_mfma_f32_16x16x32_bf16(pa, mk_frag(t1a, t1b), av[1], 0, 0, 0);
            av[2] = __builtin_amdgcn_mfma_f32_16x16x32_bf16(pa, mk_frag(t2a, t2b), av[2], 0, 0, 0);
            av[3] = __builtin_amdgcn_mfma_f32_16x16x32_bf16(pa, mk_frag(t3a, t3b), av[3], 0, 0, 0);
            v2i t4a = tr_read(abase + (ntb + 4) * 1040);
            v2i t4b = tr_read(abase + (ntb + 4) * 1040 + 128);
            v2i t5a = tr_read(abase + (ntb + 5) * 1040);
            v2i t5b = tr_read(abase + (ntb + 5) * 1040 + 128);
            v2i t6a = tr_read(abase + (ntb + 6) * 1040);
            v2i t6b = tr_read(abase + (ntb + 6) * 1040 + 128);
            v2i t7a = tr_read(abase + (ntb + 7) * 1040);
            v2i t7b = tr_read(abase + (ntb + 7) * 1040 + 128);
            asm volatile("s_waitcnt lgkmcnt(0)" ::: "memory");
            __builtin_amdgcn_sched_barrier(0);
            av[4] = __builtin_amdgcn_mfma_f32_16x16x32_bf16(pa, mk_frag(t4a, t4b), av[4], 0, 0, 0);
            av[5] = __builtin_amdgcn_mfma_f32_16x16x32_bf16(pa, mk_frag(t5a, t5b), av[5], 0, 0, 0);
            av[6] = __builtin_amdgcn_mfma_f32_16x16x32_bf16(pa, mk_frag(t6a, t6b), av[6], 0, 0, 0);
            av[7] = __builtin_amdgcn_mfma_f32_16x16x32_bf16(pa, mk_frag(t7a, t7b), av[7], 0, 0, 0);
        }
        __syncthreads();   // E: xb[nxt]/stats[nxt] visible; xb[cur]/pt free
    }

    // ---- final accumulation: A0/A1 atomic (tiny), V plain partial stores ----
    A0acc += __shfl_xor(A0acc, 16, 64); A0acc += __shfl_xor(A0acc, 32, 64);
    A1acc += __shfl_xor(A1acc, 16, 64); A1acc += __shfl_xor(A1acc, 32, 64);
    if (g == 0) {
        atomicAdd(A0_g + b * 32 + hqB, A0acc);
        atomicAdd(A1_g + b * 32 + hqB, A1acc);
    }
    float* vp = vpart + ((size_t)(b * KBMAX + kb) * 32) * 256;
    #pragma unroll
    for (int i = 0; i < 8; ++i) {
        int j = (ntb + i) * 16 + li;
        #pragma unroll
        for (int r = 0; r < 4; ++r) {
            int hq = MtV * 16 + g * 4 + r;
            vp[(size_t)hq * 256 + j] = av[i][r];
        }
    }
}

// ---------------------------------------------------------------------------
// V reduction: V[b][hq][j] = sum_kb Vpart[b*KBMAX+kb][hq][j].  grid (32, 32).
template<int KBMAX>
__global__ __launch_bounds__(256) void k_vred(
    const float* __restrict__ vpart, float* __restrict__ V_g)
{
    const int t = threadIdx.x;
    const int b = blockIdx.x, hq = blockIdx.y;
    const float* p = vpart + ((size_t)(b * KBMAX) * 32 + hq) * 256 + t;
    float s = 0.f;
    #pragma unroll 8
    for (int kb = 0; kb < KBMAX; ++kb)
        s += p[(size_t)kb * 8192];
    V_g[((size_t)b * 32 + hq) * 256 + t] = s;
}

// ---------------------------------------------------------------------------
// gx | gh GEMMs. grid (6, 64). chunk-0 blocks zero slot_nxt (+ out_slots last iter).
__global__ __launch_bounds__(256) void k_gates(
    const float* __restrict__ V_g, const float* __restrict__ A0_g,
    const float* __restrict__ A1_g,
    const float* __restrict__ g_in, const float* __restrict__ b_in,
    const float* __restrict__ slot_cur,
    const unsigned* __restrict__ WfT2, const unsigned* __restrict__ WhhT2,
    float* __restrict__ gxh, float* __restrict__ slot_nxt,
    float* __restrict__ out_slots)
{
    __shared__ __align__(16) float aT[1024 * 4];   // [k][rr]
    const int t = threadIdx.x;
    const int rg = blockIdx.y;
    const int chunk = blockIdx.x;
    const int row0 = rg * 4;
    float acc0 = 0.f, acc1 = 0.f, acc2 = 0.f, acc3 = 0.f;

    if (chunk == 0) {
        #pragma unroll
        for (int rr = 0; rr < 4; ++rr) {
            slot_nxt[(size_t)(row0 + rr) * 256 + t] = 0.f;
            if (out_slots) out_slots[(size_t)(row0 + rr) * 256 + t] = 0.f;
        }
    }

    if (chunk < 3) {
        const int b = rg >> 1, qi0 = (rg & 1) * 4;
        const float gt = g_in[t], bt = b_in[t];
        #pragma unroll
        for (int kk = 0; kk < 4; ++kk) {
            float4 y4;
            #pragma unroll
            for (int rr = 0; rr < 4; ++rr) {
                int hq = kk * 8 + qi0 + rr;
                float A0 = A0_g[b * 32 + hq], A1 = A1_g[b * 32 + hq];
                float den = A0 + EPSR * (float)NKV;
                float vv = V_g[((size_t)b * 32 + hq) * 256 + t];
                float yv = (gt * (vv - A1) + bt * A0) / den;
                ((float*)&y4)[rr] = yv;
            }
            *(float4*)(aT + (kk * 256 + t) * 4) = y4;
        }
        __syncthreads();
        const unsigned* wp = WfT2 + chunk * 256 + t;
        #pragma unroll 4
        for (int k2 = 0; k2 < 512; ++k2) {
            unsigned wv = wp[(size_t)k2 * 768];
            float w0 = bflo(wv), w1 = bfhi(wv);
            float4 a0 = *(const float4*)(aT + 8 * k2);
            float4 a1 = *(const float4*)(aT + 8 * k2 + 4);
            acc0 = fmaf(a0.x, w0, acc0); acc0 = fmaf(a1.x, w1, acc0);
            acc1 = fmaf(a0.y, w0, acc1); acc1 = fmaf(a1.y, w1, acc1);
            acc2 = fmaf(a0.z, w0, acc2); acc2 = fmaf(a1.z, w1, acc2);
            acc3 = fmaf(a0.w, w0, acc3); acc3 = fmaf(a1.w, w1, acc3);
        }
        float* go = gxh + (size_t)row0 * 1536 + chunk * 256 + t;
        go[0] = acc0; go[1536] = acc1; go[3072] = acc2; go[4608] = acc3;
    } else {
        const int gc = chunk - 3;
        {
            float4 y4;
            #pragma unroll
            for (int rr = 0; rr < 4; ++rr)
                ((float*)&y4)[rr] = slot_cur[(size_t)(row0 + rr) * 256 + t];
            *(float4*)(aT + t * 4) = y4;
        }
        __syncthreads();
        const unsigned* wp = WhhT2 + gc * 256 + t;
        #pragma unroll 4
        for (int k2 = 0; k2 < 128; ++k2) {
            unsigned wv = wp[(size_t)k2 * 768];
            float w0 = bflo(wv), w1 = bfhi(wv);
            float4 a0 = *(const float4*)(aT + 8 * k2);
            float4 a1 = *(const float4*)(aT + 8 * k2 + 4);
            acc0 = fmaf(a0.x, w0, acc0); acc0 = fmaf(a1.x, w1, acc0);
            acc1 = fmaf(a0.y, w0, acc1); acc1 = fmaf(a1.y, w1, acc1);
            acc2 = fmaf(a0.z, w0, acc2); acc2 = fmaf(a1.z, w1, acc2);
            acc3 = fmaf(a0.w, w0, acc3); acc3 = fmaf(a1.w, w1, acc3);
        }
        float* go = gxh + (size_t)row0 * 1536 + 768 + gc * 256 + t;
        go[0] = acc0; go[1536] = acc1; go[3072] = acc2; go[4608] = acc3;
    }
}

// ---------------------------------------------------------------------------
// Fused GRU elementwise + LN + MLP(W1,relu,W2) with h1 in LDS. grid (4, 64).
// Dual atomics: slot_nxt always; out_slots too on last iteration.
__global__ __launch_bounds__(256) void k_mlp(
    const float* __restrict__ gxh, const float* __restrict__ slot_cur,
    const float* __restrict__ bih, const float* __restrict__ bhh,
    const float* __restrict__ gm, const float* __restrict__ bm,
    const unsigned* __restrict__ W1T2, const float* __restrict__ b1,
    const unsigned* __restrict__ W2T2, const float* __restrict__ b2,
    float* __restrict__ slot_nxt, float* __restrict__ out_slots)
{
    __shared__ __align__(16) float mT[1024];
    __shared__ float sm_l[4][256];
    __shared__ float h1_l[4][256];
    __shared__ float lnst[8];
    const int t = threadIdx.x;
    const int rg = blockIdx.y, chunk = blockIdx.x;
    const int row0 = rg * 4;
    const int lane = t & 63, w = t >> 6;

    const float bi0 = bih[t], bi1 = bih[256 + t], bi2 = bih[512 + t];
    const float bh0 = bhh[t], bh1 = bhh[256 + t], bh2 = bhh[512 + t];
    float smid[4];
    #pragma unroll
    for (int rr = 0; rr < 4; ++rr) {
        const float* gr = gxh + (size_t)(row0 + rr) * 1536;
        float gx0 = gr[t], gx1 = gr[256 + t], gx2 = gr[512 + t];
        float gh0 = gr[768 + t], gh1 = gr[1024 + t], gh2 = gr[1280 + t];
        float spv = slot_cur[(size_t)(row0 + rr) * 256 + t];
        float r = 1.f / (1.f + __expf(-(gx0 + bi0 + gh0 + bh0)));
        float z = 1.f / (1.f + __expf(-(gx1 + bi1 + gh1 + bh1)));
        float n = tanhf(gx2 + bi2 + r * (gh2 + bh2));
        smid[rr] = (1.f - z) * n + z * spv;
        sm_l[rr][t] = smid[rr];
    }
    __syncthreads();
    {
        float4 v = *(const float4*)(&sm_l[w][lane * 4]);
        float s0 = v.x + v.y + v.z + v.w;
        float s1 = v.x * v.x + v.y * v.y + v.z * v.z + v.w * v.w;
        #pragma unroll
        for (int o = 32; o >= 1; o >>= 1) { s0 += __shfl_xor(s0, o, 64); s1 += __shfl_xor(s1, o, 64); }
        if (lane == 0) {
            float mu = s0 * (1.f / 256.f);
            lnst[w * 2] = mu;
            lnst[w * 2 + 1] = rsqrtf(s1 * (1.f / 256.f) - mu * mu + 1e-5f);
        }
    }
    __syncthreads();
    {
        const float gmt = gm[t], bmt = bm[t];
        float4 m4;
        #pragma unroll
        for (int rr = 0; rr < 4; ++rr)
            ((float*)&m4)[rr] = (smid[rr] - lnst[rr * 2]) * lnst[rr * 2 + 1] * gmt + bmt;
        *(float4*)(mT + t * 4) = m4;
    }
    __syncthreads();

    {
        float acc0 = 0.f, acc1 = 0.f, acc2 = 0.f, acc3 = 0.f;
        const unsigned* wp = W1T2 + chunk * 256 + t;
        #pragma unroll 4
        for (int k2 = 0; k2 < 128; ++k2) {
            unsigned wv = wp[(size_t)k2 * 1024];
            float w0 = bflo(wv), w1 = bfhi(wv);
            float4 a0 = *(const float4*)(mT + 8 * k2);
            float4 a1 = *(const float4*)(mT + 8 * k2 + 4);
            acc0 = fmaf(a0.x, w0, acc0); acc0 = fmaf(a1.x, w1, acc0);
            acc1 = fmaf(a0.y, w0, acc1); acc1 = fmaf(a1.y, w1, acc1);
            acc2 = fmaf(a0.z, w0, acc2); acc2 = fmaf(a1.z, w1, acc2);
            acc3 = fmaf(a0.w, w0, acc3); acc3 = fmaf(a1.w, w1, acc3);
        }
        const float b1t = b1[chunk * 256 + t];
        h1_l[0][t] = fmaxf(acc0 + b1t, 0.f);
        h1_l[1][t] = fmaxf(acc1 + b1t, 0.f);
        h1_l[2][t] = fmaxf(acc2 + b1t, 0.f);
        h1_l[3][t] = fmaxf(acc3 + b1t, 0.f);
    }
    __syncthreads();

    {
        float o0 = 0.f, o1 = 0.f, o2 = 0.f, o3 = 0.f;
        const unsigned* wp = W2T2 + (size_t)(chunk * 128) * 256 + t;
        #pragma unroll 4
        for (int k2 = 0; k2 < 128; ++k2) {
            unsigned wv = wp[(size_t)k2 * 256];
            float w0 = bflo(wv), w1 = bfhi(wv);
            float a00 = h1_l[0][2 * k2], a01 = h1_l[0][2 * k2 + 1];
            float a10 = h1_l[1][2 * k2], a11 = h1_l[1][2 * k2 + 1];
            float a20 = h1_l[2][2 * k2], a21 = h1_l[2][2 * k2 + 1];
            float a30 = h1_l[3][2 * k2], a31 = h1_l[3][2 * k2 + 1];
            o0 = fmaf(a00, w0, o0); o0 = fmaf(a01, w1, o0);
            o1 = fmaf(a10, w0, o1); o1 = fmaf(a11, w1, o1);
            o2 = fmaf(a20, w0, o2); o2 = fmaf(a21, w1, o2);
            o3 = fmaf(a30, w0, o3); o3 = fmaf(a31, w1, o3);
        }
        const float b2t = b2[t];
        float p0 = o0 + ((chunk == 0) ? smid[0] + b2t : 0.f);
        float p1 = o1 + ((chunk == 0) ? smid[1] + b2t : 0.f);
        float p2 = o2 + ((chunk == 0) ? smid[2] + b2t : 0.f);
        float p3 = o3 + ((chunk == 0) ? smid[3] + b2t : 0.f);
        atomicAdd(slot_nxt + (size_t)(row0 + 0) * 256 + t, p0);
        atomicAdd(slot_nxt + (size_t)(row0 + 1) * 256 + t, p1);
        atomicAdd(slot_nxt + (size_t)(row0 + 2) * 256 + t, p2);
        atomicAdd(slot_nxt + (size_t)(row0 + 3) * 256 + t, p3);
        if (out_slots) {
            atomicAdd(out_slots + (size_t)(row0 + 0) * 256 + t, p0);
            atomicAdd(out_slots + (size_t)(row0 + 1) * 256 + t, p1);
            atomicAdd(out_slots + (size_t)(row0 + 2) * 256 + t, p2);
            atomicAdd(out_slots + (size_t)(row0 + 3) * 256 + t, p3);
        }
    }
}

// ---------------------------------------------------------------------------
extern "C" void kernel_launch(void* const* d_in, const int* in_sizes, int n_in,
                              void* d_out, int out_size, void* d_ws, size_t ws_size,
                              hipStream_t stream) {
    const float* inp     = (const float*)d_in[0];
    const float* slots0  = (const float*)d_in[1];
    const float* ln_in_g = (const float*)d_in[2];
    const float* ln_in_b = (const float*)d_in[3];
    const float* ln_s_g  = (const float*)d_in[4];
    const float* ln_s_b  = (const float*)d_in[5];
    const float* ln_m_g  = (const float*)d_in[6];
    const float* ln_m_b  = (const float*)d_in[7];
    const float* Wq  = (const float*)d_in[8];
    const float* Wk  = (const float*)d_in[9];
    const float* Wv  = (const float*)d_in[10];
    const float* Wih = (const float*)d_in[11];
    const float* Whh = (const float*)d_in[12];
    const float* bih = (const float*)d_in[13];
    const float* bhh = (const float*)d_in[14];
    const float* W1  = (const float*)d_in[15];
    const float* b1  = (const float*)d_in[16];
    const float* W2  = (const float*)d_in[17];
    const float* b2  = (const float*)d_in[18];

    float* ws = (float*)d_ws;
    float* V_g   = ws + WS_V;
    float* A0_g  = ws + WS_A0;
    float* A1_g  = ws + WS_A1;
    float* c0_g  = ws + WS_C0;
    float* c1_g  = ws + WS_C1;
    float* slotA = ws + WS_SLOTA;
    float* slotB = ws + WS_SLOTB;
    float* wqt   = ws + WS_WQT;
    float* qf_g  = ws + WS_QF;
    float* gxh   = ws + WS_WPGXH;    // aliased with wp_bf (disjoint lifetimes)
    unsigned short* wp_bf = (unsigned short*)(ws + WS_WPGXH);
    unsigned* WfT2  = (unsigned*)(ws + WS_WFT);
    unsigned* WhhT2 = (unsigned*)(ws + WS_WHHT);
    unsigned* W1T2  = (unsigned*)(ws + WS_W1T);
    unsigned* W2T2  = (unsigned*)(ws + WS_W2T);
    float* rs_g  = ws + WS_RS;
    float* rm_g  = ws + WS_RM;
    float* vpart = ws + WS_VPART;

    const int useNC2 = (ws_size >= (size_t)(WS_VPART + 32ull * 64 * 8192) * 4) ? 1 : 0;

    float* out_slots = (float*)d_out;
    float* out_vis   = out_slots + 32 * 8 * 256;
    float* out_temp  = out_vis + 32 * 4096 * 8;

    k_tr<<<dim3(8, 8), dim3(32, 8), 0, stream>>>(Wq, wqt, 256, 256);
    k_wfold<<<768, 256, 0, stream>>>(Wih, Wv, WfT2);
    k_trpack<<<128, 256, 0, stream>>>(Whh, WhhT2, 768, 256);
    k_trpack<<<128, 256, 0, stream>>>(W1, W1T2, 1024, 256);
    k_trpack<<<512, 256, 0, stream>>>(W2, W2T2, 256, 1024);
    k_copy<<<256, 256, 0, stream>>>(slots0, slotA, 65536);

    for (int it = 0; it < 3; ++it) {
        float* cur = (it & 1) ? slotB : slotA;
        float* nxt = (it & 1) ? slotA : slotB;
        k_prep_a<<<dim3(32, 8), 256, 0, stream>>>(cur, ln_s_g, ln_s_b, wqt, qf_g,
                                                  A0_g, A1_g);
        k_prep_b<<<dim3(32, 4), 256, 0, stream>>>(qf_g, Wk, ln_in_g, ln_in_b,
                                                  wp_bf, c0_g, c1_g);
        if (useNC2) {
            if (it == 0)
                k_attn<2, 1, 0><<<dim3(64, 32), 256, 0, stream>>>(
                    inp, wp_bf, c0_g, c1_g, vpart, A0_g, A1_g, rs_g, rm_g, out_vis, out_temp);
            else if (it == 1)
                k_attn<2, 0, 0><<<dim3(64, 32), 256, 0, stream>>>(
                    inp, wp_bf, c0_g, c1_g, vpart, A0_g, A1_g, rs_g, rm_g, out_vis, out_temp);
            else
                k_attn<2, 0, 1><<<dim3(64, 32), 256, 0, stream>>>(
                    inp, wp_bf, c0_g, c1_g, vpart, A0_g, A1_g, rs_g, rm_g, out_vis, out_temp);
            k_vred<64><<<dim3(32, 32), 256, 0, stream>>>(vpart, V_g);
        } else {
            if (it == 0)
                k_attn<4, 1, 0><<<dim3(32, 32), 256, 0, stream>>>(
                    inp, wp_bf, c0_g, c1_g, vpart, A0_g, A1_g, rs_g, rm_g, out_vis, out_temp);
            else if (it == 1)
                k_attn<4, 0, 0><<<dim3(32, 32), 256, 0, stream>>>(
                    inp, wp_bf, c0_g, c1_g, vpart, A0_g, A1_g, rs_g, rm_g, out_vis, out_temp);
            else
                k_attn<4, 0, 1><<<dim3(32, 32), 256, 0, stream>>>(
                    inp, wp_bf, c0_g, c1_g, vpart, A0_g, A1_g, rs_g, rm_g, out_vis, out_temp);
            k_vred<32><<<dim3(32, 32), 256, 0, stream>>>(vpart, V_g);
        }
        k_gates<<<dim3(6, 64), 256, 0, stream>>>(
            V_g, A0_g, A1_g, ln_in_g, ln_in_b, cur, WfT2, WhhT2, gxh, nxt,
            (it == 2) ? out_slots : nullptr);
        k_mlp<<<dim3(4, 64), 256, 0, stream>>>(
            gxh, cur, bih, bhh, ln_m_g, ln_m_b, W1T2, b1, W2T2, b2, nxt,
            (it == 2) ? out_slots : nullptr);
    }
}

// Round 11
// 452.942 us; speedup vs baseline: 1.1722x; 1.0471x over previous
//
#include <hip/hip_runtime.h>
#include <math.h>

// ---------------------------------------------------------------------------
// SlotAttention fused forward. MFMA (bf16) attention path.
//   xb holds RAW bf16 x (single buffer, 4 blocks/CU);  register prefetch of
//   next chunk; pack after E barrier.  logit = rs*dot(x,w'') - rm*c1 + c0
//   P = a*rs;  rs/rm iteration-invariant (iter0 computes+stores, iters 1-2 load)
//   V partials: bf16 pk2 stores to Vpart (32MB), reduced by k_vred.
//   y-fold: updates_pre[hq,j] = (g_j*(V - A1) + b_j*A0)/(A0 + eps*N)
//   GRU/MLP: gx = yflat @ Wfold^T (Wv folded into W_ih); k_gates + fused k_mlp.
// ---------------------------------------------------------------------------

#define NKV   4096
#define DD    256
#define HQN   32
#define EPSR  1e-8f

// workspace layout (float offsets) — ws_size proven >= 74.9 MB (r10 ran NC=2)
#define WS_V      0                     // 262144
#define WS_A0     262144                // 1024
#define WS_A1     263168                // 1024
#define WS_C0     264192                // 1024
#define WS_C1     265216                // 1024
#define WS_SLOTA  266240                // 65536
#define WS_SLOTB  331776                // 65536
#define WS_WQT    397312                // 65536 fp32 Wq^T
#define WS_WPGXH  462848                // 393216 (wp_bf 131072f | gxh [256][1536])
#define WS_WFT    856064                // 393216 uints: WfoldT2 [512][768]
#define WS_WHHT   1249280               // 98304 uints:  WhhT2   [128][768]
#define WS_W1T    1347584               // 131072 uints: W1T2    [128][1024]
#define WS_W2T    1478656               // 131072 uints: W2T2    [512][256]
#define WS_RS     1609728               // 131072 fp32 rs per token
#define WS_RM     1740800               // 131072 fp32 rm per token
#define WS_VPART  1871872               // 8388608 uints: Vpart bf16x2, 32MB
// total bytes: (1871872 + 8388608) * 4 ≈ 41.0 MB

typedef float f32x4 __attribute__((ext_vector_type(4)));
typedef short s16x8 __attribute__((ext_vector_type(8)));
typedef int   v2i   __attribute__((ext_vector_type(2)));

__device__ __forceinline__ unsigned bfr(float f) {
    unsigned u = __float_as_uint(f);
    return (u + 0x7fffu + ((u >> 16) & 1u)) >> 16;
}
__device__ __forceinline__ unsigned pk2(float lo, float hi) {
    return bfr(lo) | (bfr(hi) << 16);
}
__device__ __forceinline__ float bf2f(unsigned short us) {
    return __uint_as_float((unsigned)us << 16);
}
__device__ __forceinline__ float bflo(unsigned u) { return __uint_as_float(u << 16); }
__device__ __forceinline__ float bfhi(unsigned u) { return __uint_as_float(u & 0xffff0000u); }

__device__ __forceinline__ v2i tr_read(unsigned addr) {
    v2i d;
    asm volatile("ds_read_b64_tr_b16 %0, %1" : "=v"(d) : "v"(addr));
    return d;
}
__device__ __forceinline__ s16x8 mk_frag(v2i a, v2i b) {
    union { int i[4]; s16x8 s; } u;
    u.i[0] = a.x; u.i[1] = a.y; u.i[2] = b.x; u.i[3] = b.y;
    return u.s;
}

__global__ __launch_bounds__(256) void k_copy(const float* __restrict__ in,
                                              float* __restrict__ out, int n) {
    int i = blockIdx.x * 256 + threadIdx.x;
    if (i < n) out[i] = in[i];
}

// generic 32x32 tiled fp32 transpose: in[R][C] -> out[C][R]
__global__ __launch_bounds__(256) void k_tr(const float* __restrict__ in,
                                            float* __restrict__ out, int R, int C) {
    __shared__ float tile[32][33];
    int bx = blockIdx.x * 32, by = blockIdx.y * 32;
    int x = bx + threadIdx.x;
    for (int k = 0; k < 32; k += 8) {
        int y = by + threadIdx.y + k;
        if (x < C && y < R) tile[threadIdx.y + k][threadIdx.x] = in[(size_t)y * C + x];
    }
    __syncthreads();
    int r = by + threadIdx.x;
    for (int k = 0; k < 32; k += 8) {
        int c = bx + threadIdx.y + k;
        if (c < C && r < R) out[(size_t)c * R + r] = tile[threadIdx.x][threadIdx.y + k];
    }
}

// ---------------------------------------------------------------------------
// Wfold: one block per output row c.
__global__ __launch_bounds__(256) void k_wfold(
    const float* __restrict__ Wih, const float* __restrict__ Wv,
    unsigned* __restrict__ WfT2)
{
    __shared__ float wr[256];
    const int c = blockIdx.x, t = threadIdx.x;
    wr[t] = Wih[(size_t)c * 256 + t];
    __syncthreads();
    const float2* wv2 = (const float2*)Wv;
    #pragma unroll
    for (int pp = 0; pp < 2; ++pp) {
        int P = pp * 256 + t;
        int h = P >> 7, p = P & 127;
        float f0 = 0.f, f1 = 0.f;
        #pragma unroll 8
        for (int d = 0; d < 64; ++d) {
            float a = wr[h * 64 + d];
            float2 v = wv2[(size_t)(h * 64 + d) * 128 + p];
            f0 = fmaf(a, v.x, f0); f1 = fmaf(a, v.y, f1);
        }
        WfT2[(size_t)P * 768 + c] = pk2(f0, f1);
    }
}

// transpose+pack: in fp32 [R][C] -> out uint [C/2][R]
__global__ __launch_bounds__(256) void k_trpack(
    const float* __restrict__ in, unsigned* __restrict__ out, int R, int C)
{
    const int c2 = blockIdx.x;
    const int t = threadIdx.x;
    for (int q = 0; q < R / 256; ++q) {
        int r = q * 256 + t;
        out[(size_t)c2 * R + r] = pk2(in[(size_t)r * C + 2 * c2],
                                      in[(size_t)r * C + 2 * c2 + 1]);
    }
}

// ---------------------------------------------------------------------------
// Merged slot prep: grid (32 b, 4 h). LN(slots) in LDS, qf 64-col slice
// recomputed per block, then wkq fold + c0/c1 + wp_bf write.
__global__ __launch_bounds__(256) void k_prep(
    const float* __restrict__ slots, const float* __restrict__ g_s, const float* __restrict__ b_s,
    const float* __restrict__ wqt, const float* __restrict__ Wk,
    const float* __restrict__ g_in, const float* __restrict__ b_in,
    unsigned short* __restrict__ wp_bf, float* __restrict__ c0_g, float* __restrict__ c1_g,
    float* __restrict__ A0_g, float* __restrict__ A1_g)
{
    __shared__ float s_lds[2048];
    __shared__ float qs[512];        // [qi][d]
    __shared__ float redc[4096];
    const int t = threadIdx.x;
    const int b = blockIdx.x, h = blockIdx.y;
    const int lane = t & 63, w = t >> 6;
    const float LNS = 0.125f * 1.44269504f;

    if (h == 0 && t < 32) { A0_g[b * 32 + t] = 0.f; A1_g[b * 32 + t] = 0.f; }

    // LN(slots): wave w handles rows w and w+4
    for (int r = w; r < 8; r += 4) {
        const float4 v = ((const float4*)(slots + ((size_t)b * 8 + r) * 256))[lane];
        float s0 = v.x + v.y + v.z + v.w;
        float s1 = v.x * v.x + v.y * v.y + v.z * v.z + v.w * v.w;
        #pragma unroll
        for (int o = 32; o >= 1; o >>= 1) { s0 += __shfl_xor(s0, o, 64); s1 += __shfl_xor(s1, o, 64); }
        float m = s0 * (1.f / 256.f);
        float rs = rsqrtf(s1 * (1.f / 256.f) - m * m + 1e-5f);
        float4 gg = ((const float4*)g_s)[lane];
        float4 bb = ((const float4*)b_s)[lane];
        float4 nn;
        nn.x = (v.x - m) * rs * gg.x + bb.x;
        nn.y = (v.y - m) * rs * gg.y + bb.y;
        nn.z = (v.z - m) * rs * gg.z + bb.z;
        nn.w = (v.w - m) * rs * gg.w + bb.w;
        ((float4*)(s_lds + r * 256))[lane] = nn;
    }
    __syncthreads();

    // qf slice: qf[qi][h*64+d] for qi in {t>>6, (t>>6)+4}, d = t&63
    {
        const int qi0 = t >> 6, d = t & 63;
        float a0 = 0.f, a1 = 0.f;
        #pragma unroll 8
        for (int j = 0; j < 256; ++j) {
            float wv = wqt[j * 256 + h * 64 + d];
            a0 = fmaf(s_lds[qi0 * 256 + j], wv, a0);
            a1 = fmaf(s_lds[(qi0 + 4) * 256 + j], wv, a1);
        }
        qs[qi0 * 64 + d] = a0;
        qs[(qi0 + 4) * 64 + d] = a1;
    }
    __syncthreads();

    float a2[8];
    #pragma unroll
    for (int qi = 0; qi < 8; ++qi) a2[qi] = 0.f;
    #pragma unroll 4
    for (int d = 0; d < 64; ++d) {
        float wv = Wk[(size_t)(h * 64 + d) * 256 + t];
        #pragma unroll
        for (int qi = 0; qi < 8; ++qi) a2[qi] = fmaf(qs[qi * 64 + d], wv, a2[qi]);
    }
    const float gv = g_in[t], bv = b_in[t];
    #pragma unroll
    for (int qi = 0; qi < 8; ++qi) {
        float kv = LNS * a2[qi];
        float we = kv * gv;
        wp_bf[((size_t)b * HQN + h * 8 + qi) * 256 + t] = (unsigned short)bfr(we);
        redc[qi * 256 + t] = we;
        redc[2048 + qi * 256 + t] = kv * bv;
    }
    __syncthreads();
    #pragma unroll
    for (int rep = 0; rep < 2; ++rep) {
        int r = w * 2 + rep;
        float sv1 = redc[r * 256 + lane] + redc[r * 256 + 64 + lane] +
                    redc[r * 256 + 128 + lane] + redc[r * 256 + 192 + lane];
        float sv0 = redc[2048 + r * 256 + lane] + redc[2048 + r * 256 + 64 + lane] +
                    redc[2048 + r * 256 + 128 + lane] + redc[2048 + r * 256 + 192 + lane];
        #pragma unroll
        for (int o = 32; o >= 1; o >>= 1) {
            sv1 += __shfl_xor(sv1, o, 64);
            sv0 += __shfl_xor(sv0, o, 64);
        }
        if (lane == 0) {
            c1_g[b * 32 + h * 8 + r] = sv1;
            c0_g[b * 32 + h * 8 + r] = sv0;
        }
    }
}

// ---------------------------------------------------------------------------
// k_attn helpers
__device__ __forceinline__ void load_x(const float* __restrict__ inp, int b, int n0,
                                       int tok_s, int seg8, float4* ld) {
    const float4* row4 = (const float4*)(inp + ((size_t)b * NKV + n0 + tok_s) * 256);
    #pragma unroll
    for (int u = 0; u < 8; ++u) ld[u] = row4[(u >> 2) * 32 + seg8 * 4 + (u & 3)];
}

__device__ __forceinline__ void pack_x(const float4* ld, char* dst, int tok_s, int seg8) {
    #pragma unroll
    for (int c = 0; c < 2; ++c) {
        int nt = seg8 + 8 * c;
        #pragma unroll
        for (int h = 0; h < 2; ++h) {
            float4 fa = ld[c * 4 + h * 2], fb = ld[c * 4 + h * 2 + 1];
            uint4 pk;
            pk.x = pk2(fa.x, fa.y); pk.y = pk2(fa.z, fa.w);
            pk.z = pk2(fb.x, fb.y); pk.w = pk2(fb.z, fb.w);
            *(uint4*)(dst + nt * 1040 + tok_s * 32 + h * 16) = pk;
        }
    }
}

__device__ __forceinline__ void calc_stats(const float4* ld, float* sb,
                                           float* __restrict__ rs_g, float* __restrict__ rm_g,
                                           int b, int n0, int tok_s, int seg8) {
    float s0 = 0.f, s1 = 0.f;
    #pragma unroll
    for (int u = 0; u < 8; ++u) {
        float4 v = ld[u];
        s0 += v.x + v.y + v.z + v.w;
        s1 = fmaf(v.x, v.x, s1); s1 = fmaf(v.y, v.y, s1);
        s1 = fmaf(v.z, v.z, s1); s1 = fmaf(v.w, v.w, s1);
    }
    s0 += __shfl_xor(s0, 1, 64); s1 += __shfl_xor(s1, 1, 64);
    s0 += __shfl_xor(s0, 2, 64); s1 += __shfl_xor(s1, 2, 64);
    s0 += __shfl_xor(s0, 4, 64); s1 += __shfl_xor(s1, 4, 64);
    float m  = s0 * (1.f / 256.f);
    float rs = rsqrtf(s1 * (1.f / 256.f) - m * m + 1e-5f);
    if (seg8 == 0) {
        sb[tok_s] = rs;
        sb[32 + tok_s] = rs * m;
        rs_g[b * 4096 + n0 + tok_s] = rs;
        rm_g[b * 4096 + n0 + tok_s] = rs * m;
    }
}

// ---------------------------------------------------------------------------
// Main fused MFMA pass. grid (64, 32): NC=2 chunks of 32 tokens per block.
// Single xb buffer (36KB LDS -> 4 blocks/CU); register prefetch of next chunk;
// pack after E barrier. V partials stored bf16-packed to vpart.
template<int NC, int STATS, int WVIS>
__global__ __launch_bounds__(256) void k_attn(
    const float* __restrict__ inp, const unsigned short* __restrict__ wp_bf,
    const float* __restrict__ c0_g, const float* __restrict__ c1_g,
    unsigned* __restrict__ vpart, float* __restrict__ A0_g, float* __restrict__ A1_g,
    float* __restrict__ rs_g, float* __restrict__ rm_g,
    float* __restrict__ out_vis, float* __restrict__ out_temp)
{
    constexpr int KBMAX = 128 / NC;
    __shared__ unsigned short xb[8320];         // 16640 B single buffer
    __shared__ unsigned short wl[8192];         // [hq][k] swizzled
    __shared__ unsigned short pt[1024];         // [hq][tok] swizzled bf16 P (= a*rs)
    __shared__ float stats[2][64];              // [0..32): rs, [32..64): rm
    __shared__ float redm[64];
    __shared__ float reds[64];

    const int t = threadIdx.x;
    const int l = t & 63, w = t >> 6;
    const int g = l >> 4, li = l & 15;
    const int b = blockIdx.y, kb = blockIdx.x;

    char* xbB = (char*)xb;
    char* wlB = (char*)wl;
    char* ptB = (char*)pt;
    const int tok_s = t >> 3, seg8 = t & 7;
    const int cbase = kb * NC;

    // stage W'' into LDS (swizzled rows [hq][k])
    {
        const uint4* wp4 = (const uint4*)wp_bf + ((size_t)b * 8192 + (t >> 3) * 256 + (t & 7) * 32) / 8;
        const int hq = t >> 3, sg = t & 7;
        #pragma unroll
        for (int q = 0; q < 4; ++q) {
            uint4 v = wp4[q];
            *(uint4*)(wlB + hq * 512 + (((sg * 4 + q) ^ (hq & 7)) * 16)) = v;
        }
    }

    const int Mt = w & 1, Nt = w >> 1;
    const int hqB = Nt * 16 + li;
    const float c0r = c0_g[b * 32 + hqB];
    const float c1r = c1_g[b * 32 + hqB];
    const int MtV = w >> 1, ntb = (w & 1) * 8;
    const int hqA = MtV * 16 + li;

    f32x4 av[8];
    #pragma unroll
    for (int u = 0; u < 8; ++u) av[u] = (f32x4){0.f, 0.f, 0.f, 0.f};
    float A0acc = 0.f, A1acc = 0.f;

    const unsigned xbase = (unsigned)(uintptr_t)xbB;

    // ---- prologue: chunk 0 ----
    {
        float4 ldA[8];
        load_x(inp, b, cbase * 32, tok_s, seg8, ldA);
        if (STATS) {
            calc_stats(ldA, &stats[0][0], rs_g, rm_g, b, cbase * 32, tok_s, seg8);
        } else {
            if (t < 32) stats[0][t] = rs_g[b * 4096 + cbase * 32 + t];
            else if (t < 64) stats[0][t] = rm_g[b * 4096 + cbase * 32 + t - 32];
        }
        pack_x(ldA, xbB, tok_s, seg8);
    }
    __syncthreads();   // A

    #pragma unroll
    for (int ci = 0; ci < NC; ++ci) {
        const int cur = ci & 1, nxt = cur ^ 1;
        const int n0 = (cbase + ci) * 32;

        // ---- issue next-chunk loads (latency hidden under this chunk) ----
        float4 ldN[8];
        if (ci < NC - 1) load_x(inp, b, n0 + 32, tok_s, seg8, ldN);
        __builtin_amdgcn_sched_barrier(0);

        // ---- S = X * W''^T (raw-x accumulate) ----
        f32x4 accS = (f32x4){0.f, 0.f, 0.f, 0.f};
        #pragma unroll
        for (int kk = 0; kk < 8; ++kk) {
            s16x8 af = *(const s16x8*)(xbB + (kk * 2 + (g >> 1)) * 1040 +
                                       (Mt * 16 + li) * 32 + (g & 1) * 16);
            s16x8 bf = *(const s16x8*)(wlB + hqB * 512 + (((kk * 4 + g) ^ (hqB & 7)) * 16));
            accS = __builtin_amdgcn_mfma_f32_16x16x32_bf16(af, bf, accS, 0, 0, 0);
        }

        // ---- logits + merged-barrier joint softmax over 32 hq ----
        float lg[4], rsv[4], rmv[4], mh[4], ex[4], aa[4];
        #pragma unroll
        for (int r = 0; r < 4; ++r) {
            int tokr = Mt * 16 + g * 4 + r;
            rsv[r] = stats[cur][tokr];
            rmv[r] = stats[cur][32 + tokr];
            lg[r] = fmaf(rsv[r], accS[r], fmaf(-rmv[r], c1r, c0r));
        }
        #pragma unroll
        for (int r = 0; r < 4; ++r) {
            float v = lg[r];
            v = fmaxf(v, __shfl_xor(v, 1, 64));
            v = fmaxf(v, __shfl_xor(v, 2, 64));
            v = fmaxf(v, __shfl_xor(v, 4, 64));
            v = fmaxf(v, __shfl_xor(v, 8, 64));
            mh[r] = v;
            ex[r] = exp2f(lg[r] - v);
            float s = ex[r];
            s += __shfl_xor(s, 1, 64);
            s += __shfl_xor(s, 2, 64);
            s += __shfl_xor(s, 4, 64);
            s += __shfl_xor(s, 8, 64);
            if (li == 0) {
                int tokr = Mt * 16 + g * 4 + r;
                redm[tokr * 2 + Nt] = v;
                reds[tokr * 2 + Nt] = s;
            }
        }
        __syncthreads();   // B
        #pragma unroll
        for (int r = 0; r < 4; ++r) {
            int tokr = Mt * 16 + g * 4 + r;
            float m0 = redm[tokr * 2], m1 = redm[tokr * 2 + 1];
            float mx = fmaxf(m0, m1);
            float tot = reds[tokr * 2] * exp2f(m0 - mx) + reds[tokr * 2 + 1] * exp2f(m1 - mx);
            aa[r] = ex[r] * (exp2f(mh[r] - mx) / tot);
            A0acc += aa[r];
            A1acc = fmaf(aa[r], rmv[r], A1acc);
        }
        {
            uint2 pw;
            pw.x = pk2(aa[0] * rsv[0], aa[1] * rsv[1]);
            pw.y = pk2(aa[2] * rsv[2], aa[3] * rsv[3]);
            int tokb = Mt * 16 + g * 4;
            int slot = (tokb >> 3) ^ ((hqB >> 1) & 3);
            *(uint2*)(ptB + hqB * 64 + slot * 16 + (tokb & 7) * 2) = pw;
        }
        __syncthreads();   // D: P ready

        if (WVIS) {
            int tk = t >> 3, q = t & 7;
            float sv = 0.f;
            #pragma unroll
            for (int h = 0; h < 4; ++h) {
                int hq = h * 8 + q;
                int slot = (tk >> 3) ^ ((hq >> 1) & 3);
                sv += bf2f(*(const unsigned short*)(ptB + hq * 64 + slot * 16 + (tk & 7) * 2));
            }
            float vv = sv / stats[cur][tk];
            size_t o = ((size_t)b * NKV + n0 + tk) * 8 + q;
            out_vis[o] = vv; out_temp[o] = vv;
        }

        // ---- next-chunk stats (no race: writes stats[nxt]) ----
        if (ci < NC - 1) {
            if (STATS) {
                calc_stats(ldN, &stats[nxt][0], rs_g, rm_g, b, n0 + 32, tok_s, seg8);
            } else {
                if (t < 32) stats[nxt][t] = rs_g[b * 4096 + n0 + 32 + t];
                else if (t < 64) stats[nxt][t] = rm_g[b * 4096 + n0 + 32 + t - 32];
            }
        }

        // ---- V += P^T(A) * X(B) via tr-reads ----
        {
            s16x8 pa = *(const s16x8*)(ptB + hqA * 64 + ((g ^ ((hqA >> 1) & 3)) * 16));
            unsigned abase = xbase + g * 256 + li * 8;
            v2i t0a = tr_read(abase + (ntb + 0) * 1040);
            v2i t0b = tr_read(abase + (ntb + 0) * 1040 + 128);
            v2i t1a = tr_read(abase + (ntb + 1) * 1040);
            v2i t1b = tr_read(abase + (ntb + 1) * 1040 + 128);
            v2i t2a = tr_read(abase + (ntb + 2) * 1040);
            v2i t2b = tr_read(abase + (ntb + 2) * 1040 + 128);
            v2i t3a = tr_read(abase + (ntb + 3) * 1040);
            v2i t3b = tr_read(abase + (ntb + 3) * 1040 + 128);
            asm volatile("s_waitcnt lgkmcnt(0)" ::: "memory");
            __builtin_amdgcn_sched_barrier(0);
            av[0] = __builtin_amdgcn_mfma_f32_16x16x32_bf16(pa, mk_frag(t0a, t0b), av[0], 0, 0, 0);
            av[1] = __builtin_amdgcn_mfma_f32_16x16x32_bf16(pa, mk_frag(t1a, t1b), av[1], 0, 0, 0);
            av[2] = __builtin_amdgcn_mfma_f32_16x16x32_bf16(pa, mk_frag(t2a, t2b), av[2], 0, 0, 0);
            av[3] = __builtin_amdgcn_mfma_f32_16x16x32_bf16(pa, mk_frag(t3a, t3b), av[3], 0, 0, 0);
            v2i t4a = tr_read(abase + (ntb + 4) * 1040);
            v2i t4b = tr_read(abase + (ntb + 4) * 1040 + 128);
            v2i t5a = tr_read(abase + (ntb + 5) * 1040);
            v2i t5b = tr_read(abase + (ntb + 5) * 1040 + 128);
            v2i t6a = tr_read(abase + (ntb + 6) * 1040);
            v2i t6b = tr_read(abase + (ntb + 6) * 1040 + 128);
            v2i t7a = tr_read(abase + (ntb + 7) * 1040);
            v2i t7b = tr_read(abase + (ntb + 7) * 1040 + 128);
            asm volatile("s_waitcnt lgkmcnt(0)" ::: "memory");
            __builtin_amdgcn_sched_barrier(0);
            av[4] = __builtin_amdgcn_mfma_f32_16x16x32_bf16(pa, mk_frag(t4a, t4b), av[4], 0, 0, 0);
            av[5] = __builtin_amdgcn_mfma_f32_16x16x32_bf16(pa, mk_frag(t5a, t5b), av[5], 0, 0, 0);
            av[6] = __builtin_amdgcn_mfma_f32_16x16x32_bf16(pa, mk_frag(t6a, t6b), av[6], 0, 0, 0);
            av[7] = __builtin_amdgcn_mfma_f32_16x16x32_bf16(pa, mk_frag(t7a, t7b), av[7], 0, 0, 0);
        }
        __syncthreads();   // E: all xb/pt reads complete

        // ---- pack next chunk into xb (safe after E); A barrier ----
        if (ci < NC - 1) {
            pack_x(ldN, xbB, tok_s, seg8);
            __syncthreads();   // A
        }
    }

    // ---- final accumulation: A0/A1 atomic (tiny), V bf16 partial stores ----
    A0acc += __shfl_xor(A0acc, 16, 64); A0acc += __shfl_xor(A0acc, 32, 64);
    A1acc += __shfl_xor(A1acc, 16, 64); A1acc += __shfl_xor(A1acc, 32, 64);
    if (g == 0) {
        atomicAdd(A0_g + b * 32 + hqB, A0acc);
        atomicAdd(A1_g + b * 32 + hqB, A1acc);
    }
    // vpart layout: uint at ((blk*32+hq)*8 + jp)*16 + li holds
    //   lo -> V[hq][32*jp+li], hi -> V[hq][32*jp+16+li], jp = (ntb+i)/2
    {
        const size_t blk = (size_t)b * KBMAX + kb;
        #pragma unroll
        for (int r = 0; r < 4; ++r) {
            int hq = MtV * 16 + g * 4 + r;
            unsigned* vp = vpart + (blk * 32 + hq) * 128 + li;
            #pragma unroll
            for (int ip = 0; ip < 4; ++ip) {
                unsigned u = pk2(av[2 * ip][r], av[2 * ip + 1][r]);
                int jp = (ntb >> 1) + ip;
                vp[jp * 16] = u;
            }
        }
    }
}

// ---------------------------------------------------------------------------
// V reduction (bf16 partials): grid (32 b, 16). Each block: 2 hq rows.
template<int KBMAX>
__global__ __launch_bounds__(256) void k_vred(
    const unsigned* __restrict__ vpart, float* __restrict__ V_g)
{
    const int t = threadIdx.x;
    const int b = blockIdx.x;
    const int hq = blockIdx.y * 2 + (t >> 7);
    const int tl = t & 127;
    const unsigned* p = vpart + ((size_t)(b * KBMAX) * 32 + hq) * 128 + tl;
    float lo = 0.f, hi = 0.f;
    #pragma unroll 8
    for (int kb = 0; kb < KBMAX; ++kb) {
        unsigned u = p[(size_t)kb * 4096];
        lo += bflo(u); hi += bfhi(u);
    }
    const int jp = tl >> 4, li = tl & 15;
    float* vo = V_g + ((size_t)b * 32 + hq) * 256 + jp * 32 + li;
    vo[0]  = lo;
    vo[16] = hi;
}

// ---------------------------------------------------------------------------
// gx | gh GEMMs. grid (6, 64). chunk-0 blocks zero slot_nxt (+ out_slots last iter).
__global__ __launch_bounds__(256) void k_gates(
    const float* __restrict__ V_g, const float* __restrict__ A0_g,
    const float* __restrict__ A1_g,
    const float* __restrict__ g_in, const float* __restrict__ b_in,
    const float* __restrict__ slot_cur,
    const unsigned* __restrict__ WfT2, const unsigned* __restrict__ WhhT2,
    float* __restrict__ gxh, float* __restrict__ slot_nxt,
    float* __restrict__ out_slots)
{
    __shared__ __align__(16) float aT[1024 * 4];   // [k][rr]
    const int t = threadIdx.x;
    const int rg = blockIdx.y;
    const int chunk = blockIdx.x;
    const int row0 = rg * 4;
    float acc0 = 0.f, acc1 = 0.f, acc2 = 0.f, acc3 = 0.f;

    if (chunk == 0) {
        #pragma unroll
        for (int rr = 0; rr < 4; ++rr) {
            slot_nxt[(size_t)(row0 + rr) * 256 + t] = 0.f;
            if (out_slots) out_slots[(size_t)(row0 + rr) * 256 + t] = 0.f;
        }
    }

    if (chunk < 3) {
        const int b = rg >> 1, qi0 = (rg & 1) * 4;
        const float gt = g_in[t], bt = b_in[t];
        #pragma unroll
        for (int kk = 0; kk < 4; ++kk) {
            float4 y4;
            #pragma unroll
            for (int rr = 0; rr < 4; ++rr) {
                int hq = kk * 8 + qi0 + rr;
                float A0 = A0_g[b * 32 + hq], A1 = A1_g[b * 32 + hq];
                float den = A0 + EPSR * (float)NKV;
                float vv = V_g[((size_t)b * 32 + hq) * 256 + t];
                float yv = (gt * (vv - A1) + bt * A0) / den;
                ((float*)&y4)[rr] = yv;
            }
            *(float4*)(aT + (kk * 256 + t) * 4) = y4;
        }
        __syncthreads();
        const unsigned* wp = WfT2 + chunk * 256 + t;
        #pragma unroll 4
        for (int k2 = 0; k2 < 512; ++k2) {
            unsigned wv = wp[(size_t)k2 * 768];
            float w0 = bflo(wv), w1 = bfhi(wv);
            float4 a0 = *(const float4*)(aT + 8 * k2);
            float4 a1 = *(const float4*)(aT + 8 * k2 + 4);
            acc0 = fmaf(a0.x, w0, acc0); acc0 = fmaf(a1.x, w1, acc0);
            acc1 = fmaf(a0.y, w0, acc1); acc1 = fmaf(a1.y, w1, acc1);
            acc2 = fmaf(a0.z, w0, acc2); acc2 = fmaf(a1.z, w1, acc2);
            acc3 = fmaf(a0.w, w0, acc3); acc3 = fmaf(a1.w, w1, acc3);
        }
        float* go = gxh + (size_t)row0 * 1536 + chunk * 256 + t;
        go[0] = acc0; go[1536] = acc1; go[3072] = acc2; go[4608] = acc3;
    } else {
        const int gc = chunk - 3;
        {
            float4 y4;
            #pragma unroll
            for (int rr = 0; rr < 4; ++rr)
                ((float*)&y4)[rr] = slot_cur[(size_t)(row0 + rr) * 256 + t];
            *(float4*)(aT + t * 4) = y4;
        }
        __syncthreads();
        const unsigned* wp = WhhT2 + gc * 256 + t;
        #pragma unroll 4
        for (int k2 = 0; k2 < 128; ++k2) {
            unsigned wv = wp[(size_t)k2 * 768];
            float w0 = bflo(wv), w1 = bfhi(wv);
            float4 a0 = *(const float4*)(aT + 8 * k2);
            float4 a1 = *(const float4*)(aT + 8 * k2 + 4);
            acc0 = fmaf(a0.x, w0, acc0); acc0 = fmaf(a1.x, w1, acc0);
            acc1 = fmaf(a0.y, w0, acc1); acc1 = fmaf(a1.y, w1, acc1);
            acc2 = fmaf(a0.z, w0, acc2); acc2 = fmaf(a1.z, w1, acc2);
            acc3 = fmaf(a0.w, w0, acc3); acc3 = fmaf(a1.w, w1, acc3);
        }
        float* go = gxh + (size_t)row0 * 1536 + 768 + gc * 256 + t;
        go[0] = acc0; go[1536] = acc1; go[3072] = acc2; go[4608] = acc3;
    }
}

// ---------------------------------------------------------------------------
// Fused GRU elementwise + LN + MLP(W1,relu,W2) with h1 in LDS. grid (4, 64).
__global__ __launch_bounds__(256) void k_mlp(
    const float* __restrict__ gxh, const float* __restrict__ slot_cur,
    const float* __restrict__ bih, const float* __restrict__ bhh,
    const float* __restrict__ gm, const float* __restrict__ bm,
    const unsigned* __restrict__ W1T2, const float* __restrict__ b1,
    const unsigned* __restrict__ W2T2, const float* __restrict__ b2,
    float* __restrict__ slot_nxt, float* __restrict__ out_slots)
{
    __shared__ __align__(16) float mT[1024];
    __shared__ float sm_l[4][256];
    __shared__ float h1_l[4][256];
    __shared__ float lnst[8];
    const int t = threadIdx.x;
    const int rg = blockIdx.y, chunk = blockIdx.x;
    const int row0 = rg * 4;
    const int lane = t & 63, w = t >> 6;

    const float bi0 = bih[t], bi1 = bih[256 + t], bi2 = bih[512 + t];
    const float bh0 = bhh[t], bh1 = bhh[256 + t], bh2 = bhh[512 + t];
    float smid[4];
    #pragma unroll
    for (int rr = 0; rr < 4; ++rr) {
        const float* gr = gxh + (size_t)(row0 + rr) * 1536;
        float gx0 = gr[t], gx1 = gr[256 + t], gx2 = gr[512 + t];
        float gh0 = gr[768 + t], gh1 = gr[1024 + t], gh2 = gr[1280 + t];
        float spv = slot_cur[(size_t)(row0 + rr) * 256 + t];
        float r = 1.f / (1.f + __expf(-(gx0 + bi0 + gh0 + bh0)));
        float z = 1.f / (1.f + __expf(-(gx1 + bi1 + gh1 + bh1)));
        float n = tanhf(gx2 + bi2 + r * (gh2 + bh2));
        smid[rr] = (1.f - z) * n + z * spv;
        sm_l[rr][t] = smid[rr];
    }
    __syncthreads();
    {
        float4 v = *(const float4*)(&sm_l[w][lane * 4]);
        float s0 = v.x + v.y + v.z + v.w;
        float s1 = v.x * v.x + v.y * v.y + v.z * v.z + v.w * v.w;
        #pragma unroll
        for (int o = 32; o >= 1; o >>= 1) { s0 += __shfl_xor(s0, o, 64); s1 += __shfl_xor(s1, o, 64); }
        if (lane == 0) {
            float mu = s0 * (1.f / 256.f);
            lnst[w * 2] = mu;
            lnst[w * 2 + 1] = rsqrtf(s1 * (1.f / 256.f) - mu * mu + 1e-5f);
        }
    }
    __syncthreads();
    {
        const float gmt = gm[t], bmt = bm[t];
        float4 m4;
        #pragma unroll
        for (int rr = 0; rr < 4; ++rr)
            ((float*)&m4)[rr] = (smid[rr] - lnst[rr * 2]) * lnst[rr * 2 + 1] * gmt + bmt;
        *(float4*)(mT + t * 4) = m4;
    }
    __syncthreads();

    {
        float acc0 = 0.f, acc1 = 0.f, acc2 = 0.f, acc3 = 0.f;
        const unsigned* wp = W1T2 + chunk * 256 + t;
        #pragma unroll 4
        for (int k2 = 0; k2 < 128; ++k2) {
            unsigned wv = wp[(size_t)k2 * 1024];
            float w0 = bflo(wv), w1 = bfhi(wv);
            float4 a0 = *(const float4*)(mT + 8 * k2);
            float4 a1 = *(const float4*)(mT + 8 * k2 + 4);
            acc0 = fmaf(a0.x, w0, acc0); acc0 = fmaf(a1.x, w1, acc0);
            acc1 = fmaf(a0.y, w0, acc1); acc1 = fmaf(a1.y, w1, acc1);
            acc2 = fmaf(a0.z, w0, acc2); acc2 = fmaf(a1.z, w1, acc2);
            acc3 = fmaf(a0.w, w0, acc3); acc3 = fmaf(a1.w, w1, acc3);
        }
        const float b1t = b1[chunk * 256 + t];
        h1_l[0][t] = fmaxf(acc0 + b1t, 0.f);
        h1_l[1][t] = fmaxf(acc1 + b1t, 0.f);
        h1_l[2][t] = fmaxf(acc2 + b1t, 0.f);
        h1_l[3][t] = fmaxf(acc3 + b1t, 0.f);
    }
    __syncthreads();

    {
        float o0 = 0.f, o1 = 0.f, o2 = 0.f, o3 = 0.f;
        const unsigned* wp = W2T2 + (size_t)(chunk * 128) * 256 + t;
        #pragma unroll 4
        for (int k2 = 0; k2 < 128; ++k2) {
            unsigned wv = wp[(size_t)k2 * 256];
            float w0 = bflo(wv), w1 = bfhi(wv);
            float a00 = h1_l[0][2 * k2], a01 = h1_l[0][2 * k2 + 1];
            float a10 = h1_l[1][2 * k2], a11 = h1_l[1][2 * k2 + 1];
            float a20 = h1_l[2][2 * k2], a21 = h1_l[2][2 * k2 + 1];
            float a30 = h1_l[3][2 * k2], a31 = h1_l[3][2 * k2 + 1];
            o0 = fmaf(a00, w0, o0); o0 = fmaf(a01, w1, o0);
            o1 = fmaf(a10, w0, o1); o1 = fmaf(a11, w1, o1);
            o2 = fmaf(a20, w0, o2); o2 = fmaf(a21, w1, o2);
            o3 = fmaf(a30, w0, o3); o3 = fmaf(a31, w1, o3);
        }
        const float b2t = b2[t];
        float p0 = o0 + ((chunk == 0) ? smid[0] + b2t : 0.f);
        float p1 = o1 + ((chunk == 0) ? smid[1] + b2t : 0.f);
        float p2 = o2 + ((chunk == 0) ? smid[2] + b2t : 0.f);
        float p3 = o3 + ((chunk == 0) ? smid[3] + b2t : 0.f);
        atomicAdd(slot_nxt + (size_t)(row0 + 0) * 256 + t, p0);
        atomicAdd(slot_nxt + (size_t)(row0 + 1) * 256 + t, p1);
        atomicAdd(slot_nxt + (size_t)(row0 + 2) * 256 + t, p2);
        atomicAdd(slot_nxt + (size_t)(row0 + 3) * 256 + t, p3);
        if (out_slots) {
            atomicAdd(out_slots + (size_t)(row0 + 0) * 256 + t, p0);
            atomicAdd(out_slots + (size_t)(row0 + 1) * 256 + t, p1);
            atomicAdd(out_slots + (size_t)(row0 + 2) * 256 + t, p2);
            atomicAdd(out_slots + (size_t)(row0 + 3) * 256 + t, p3);
        }
    }
}

// ---------------------------------------------------------------------------
extern "C" void kernel_launch(void* const* d_in, const int* in_sizes, int n_in,
                              void* d_out, int out_size, void* d_ws, size_t ws_size,
                              hipStream_t stream) {
    const float* inp     = (const float*)d_in[0];
    const float* slots0  = (const float*)d_in[1];
    const float* ln_in_g = (const float*)d_in[2];
    const float* ln_in_b = (const float*)d_in[3];
    const float* ln_s_g  = (const float*)d_in[4];
    const float* ln_s_b  = (const float*)d_in[5];
    const float* ln_m_g  = (const float*)d_in[6];
    const float* ln_m_b  = (const float*)d_in[7];
    const float* Wq  = (const float*)d_in[8];
    const float* Wk  = (const float*)d_in[9];
    const float* Wv  = (const float*)d_in[10];
    const float* Wih = (const float*)d_in[11];
    const float* Whh = (const float*)d_in[12];
    const float* bih = (const float*)d_in[13];
    const float* bhh = (const float*)d_in[14];
    const float* W1  = (const float*)d_in[15];
    const float* b1  = (const float*)d_in[16];
    const float* W2  = (const float*)d_in[17];
    const float* b2  = (const float*)d_in[18];

    float* ws = (float*)d_ws;
    float* V_g   = ws + WS_V;
    float* A0_g  = ws + WS_A0;
    float* A1_g  = ws + WS_A1;
    float* c0_g  = ws + WS_C0;
    float* c1_g  = ws + WS_C1;
    float* slotA = ws + WS_SLOTA;
    float* slotB = ws + WS_SLOTB;
    float* wqt   = ws + WS_WQT;
    float* gxh   = ws + WS_WPGXH;    // aliased with wp_bf (disjoint lifetimes)
    unsigned short* wp_bf = (unsigned short*)(ws + WS_WPGXH);
    unsigned* WfT2  = (unsigned*)(ws + WS_WFT);
    unsigned* WhhT2 = (unsigned*)(ws + WS_WHHT);
    unsigned* W1T2  = (unsigned*)(ws + WS_W1T);
    unsigned* W2T2  = (unsigned*)(ws + WS_W2T);
    float* rs_g  = ws + WS_RS;
    float* rm_g  = ws + WS_RM;
    unsigned* vpart = (unsigned*)(ws + WS_VPART);

    float* out_slots = (float*)d_out;
    float* out_vis   = out_slots + 32 * 8 * 256;
    float* out_temp  = out_vis + 32 * 4096 * 8;

    k_tr<<<dim3(8, 8), dim3(32, 8), 0, stream>>>(Wq, wqt, 256, 256);
    k_wfold<<<768, 256, 0, stream>>>(Wih, Wv, WfT2);
    k_trpack<<<128, 256, 0, stream>>>(Whh, WhhT2, 768, 256);
    k_trpack<<<128, 256, 0, stream>>>(W1, W1T2, 1024, 256);
    k_trpack<<<512, 256, 0, stream>>>(W2, W2T2, 256, 1024);
    k_copy<<<256, 256, 0, stream>>>(slots0, slotA, 65536);

    for (int it = 0; it < 3; ++it) {
        float* cur = (it & 1) ? slotB : slotA;
        float* nxt = (it & 1) ? slotA : slotB;
        k_prep<<<dim3(32, 4), 256, 0, stream>>>(cur, ln_s_g, ln_s_b, wqt, Wk,
                                                ln_in_g, ln_in_b, wp_bf,
                                                c0_g, c1_g, A0_g, A1_g);
        if (it == 0)
            k_attn<2, 1, 0><<<dim3(64, 32), 256, 0, stream>>>(
                inp, wp_bf, c0_g, c1_g, vpart, A0_g, A1_g, rs_g, rm_g, out_vis, out_temp);
        else if (it == 1)
            k_attn<2, 0, 0><<<dim3(64, 32), 256, 0, stream>>>(
                inp, wp_bf, c0_g, c1_g, vpart, A0_g, A1_g, rs_g, rm_g, out_vis, out_temp);
        else
            k_attn<2, 0, 1><<<dim3(64, 32), 256, 0, stream>>>(
                inp, wp_bf, c0_g, c1_g, vpart, A0_g, A1_g, rs_g, rm_g, out_vis, out_temp);
        k_vred<64><<<dim3(32, 16), 256, 0, stream>>>(vpart, V_g);
        k_gates<<<dim3(6, 64), 256, 0, stream>>>(
            V_g, A0_g, A1_g, ln_in_g, ln_in_b, cur, WfT2, WhhT2, gxh, nxt,
            (it == 2) ? out_slots : nullptr);
        k_mlp<<<dim3(4, 64), 256, 0, stream>>>(
            gxh, cur, bih, bhh, ln_m_g, ln_m_b, W1T2, b1, W2T2, b2, nxt,
            (it == 2) ? out_slots : nullptr);
    }
}